// Round 1
// baseline (527.889 us; speedup 1.0000x reference)
//
#include <hip/hip_runtime.h>

#define B_SZ 4096
#define E_EXP 20
#define NE 21  // 20 experts + gate share the trunk

typedef unsigned short u16;
typedef __bf16 bf16x8 __attribute__((ext_vector_type(8)));
typedef u16 u16x8 __attribute__((ext_vector_type(8)));
typedef u16 u16x4 __attribute__((ext_vector_type(4)));
typedef float floatx4 __attribute__((ext_vector_type(4)));

static __device__ __forceinline__ u16 f2bf(float f) {
  unsigned u = __builtin_bit_cast(unsigned, f);
  u += 0x7fffu + ((u >> 16) & 1u);  // RNE
  return (u16)(u >> 16);
}

static __device__ __forceinline__ float elu1(float v) {
  return v > 0.f ? v : (__expf(v) - 1.f);
}

static __device__ __forceinline__ bf16x8 ld_bf8(const u16* p) {
  u16x8 v = *reinterpret_cast<const u16x8*>(p);
  return __builtin_bit_cast(bf16x8, v);
}

// async global->LDS DMA, 16B per lane. LDS dest is wave-uniform base +
// lane*16 — lds ptr must be linear in thread order (no padding!).
static __device__ __forceinline__ void gld_lds16(const u16* g, u16* l) {
  __builtin_amdgcn_global_load_lds(
      (const __attribute__((address_space(1))) unsigned int*)g,
      (__attribute__((address_space(3))) unsigned int*)l, 16, 0, 0);
}

// ---------------- prep: obs convert + bias concat, one dispatch ----------

__global__ void prep_small_kernel(
    const float* __restrict__ obs, u16* __restrict__ obs_bf,
    const float* __restrict__ eb1, const float* __restrict__ gb1,
    const float* __restrict__ eb2, const float* __restrict__ gb2,
    const float* __restrict__ eb3, const float* __restrict__ gb3,
    float* __restrict__ b1, float* __restrict__ b2, float* __restrict__ b3) {
  int bid = blockIdx.x;
  if (bid < 2048) {  // obs: B_SZ*512 floats, 4/thread
    int i = (bid * 256 + threadIdx.x) * 4;
    float4 v = *reinterpret_cast<const float4*>(obs + i);
    u16x4 o;
    o.x = f2bf(v.x); o.y = f2bf(v.y); o.z = f2bf(v.z); o.w = f2bf(v.w);
    *reinterpret_cast<u16x4*>(obs_bf + i) = o;
  } else {
    int i = (bid - 2048) * 256 + threadIdx.x;
    const int S1 = NE * 1024, S2 = NE * 512, S3 = NE * 256;
    if (i < S1) {
      b1[i] = (i < E_EXP * 1024) ? eb1[i] : gb1[i - E_EXP * 1024];
    } else if (i < S1 + S2) {
      int j = i - S1;
      b2[j] = (j < E_EXP * 512) ? eb2[j] : gb2[j - E_EXP * 512];
    } else if (i < S1 + S2 + S3) {
      int j = i - S1 - S2;
      b3[j] = (j < E_EXP * 256) ? eb3[j] : gb3[j - E_EXP * 256];
    }
  }
}

// ---------------- all weight transposes, one job-table dispatch ----------
#define TRANS_BLOCKS 6132

__global__ __launch_bounds__(256) void transpose_all_kernel(
    const float* __restrict__ eW1, const float* __restrict__ gW1,
    const float* __restrict__ eW2, const float* __restrict__ gW2,
    const float* __restrict__ eW3, const float* __restrict__ gW3,
    const float* __restrict__ eW4, const float* __restrict__ gW4,
    u16* __restrict__ W1t, u16* __restrict__ W2t, u16* __restrict__ W3t,
    u16* __restrict__ W4t, u16* __restrict__ gW4t) {
  int f = blockIdx.x;
  const float *srcE, *srcG;
  u16* dstBase;
  int rem, K, N, Nout, kxt, tpm, nm;
  if (f < 2688) {
    rem = f;        srcE = eW1; srcG = gW1; dstBase = W1t;
    K = 512;  N = 1024; Nout = 1024; kxt = 8;  tpm = 128; nm = 20;
  } else if (f < 5376) {
    rem = f - 2688; srcE = eW2; srcG = gW2; dstBase = W2t;
    K = 1024; N = 512;  Nout = 512;  kxt = 16; tpm = 128; nm = 20;
  } else if (f < 6048) {
    rem = f - 5376; srcE = eW3; srcG = gW3; dstBase = W3t;
    K = 512;  N = 256;  Nout = 256;  kxt = 8;  tpm = 32;  nm = 20;
  } else if (f < 6128) {
    rem = f - 6048; srcE = eW4; srcG = nullptr; dstBase = W4t;
    K = 256;  N = 32;   Nout = 32;   kxt = 4;  tpm = 4;   nm = 99;
  } else {
    rem = f - 6128; srcE = gW4; srcG = nullptr; dstBase = gW4t;
    K = 256;  N = 20;   Nout = 32;   kxt = 4;  tpm = 4;   nm = 99;
  }
  int mat = rem / tpm;
  int t = rem % tpm;
  const float* src = (mat < nm) ? (srcE + (long)mat * K * N) : srcG;
  u16* dst = dstBase + (long)mat * Nout * K;
  int kbase = (t % kxt) * 64;
  int nbase = (t / kxt) * 64;

  __shared__ float tl[64][65];
  int tid = threadIdx.x;
  int kk = tid >> 4;        // 0..15
  int n4 = (tid & 15) * 4;  // 0..60
#pragma unroll
  for (int p = 0; p < 4; ++p) {
    int k = kbase + p * 16 + kk;  // always < K (grid exact)
    int n = nbase + n4;
    float4 v = make_float4(0.f, 0.f, 0.f, 0.f);
    if (n + 3 < N) {
      v = *reinterpret_cast<const float4*>(&src[(long)k * N + n]);
    } else {
      float* vp = &v.x;
      for (int j = 0; j < 4; ++j)
        if (n + j < N) vp[j] = src[(long)k * N + n + j];
    }
    tl[p * 16 + kk][n4 + 0] = v.x;
    tl[p * 16 + kk][n4 + 1] = v.y;
    tl[p * 16 + kk][n4 + 2] = v.z;
    tl[p * 16 + kk][n4 + 3] = v.w;
  }
  __syncthreads();

  int kk8 = (tid & 7) * 8;
#pragma unroll
  for (int p = 0; p < 2; ++p) {
    int ln = p * 32 + (tid >> 3);  // 0..63
    int n = nbase + ln;
    if (n < Nout) {
      u16x8 o;
#pragma unroll
      for (int j = 0; j < 8; ++j) o[j] = f2bf(tl[kk8 + j][ln]);
      *reinterpret_cast<u16x8*>(&dst[(long)n * K + kbase + kk8]) = o;
    }
  }
}

// ---------------- grouped GEMM + bias + ELU, 256x256 8-phase -------------
// C[M,N] = elu(A[M,K] @ Wt[N,K]^T + bias), bf16 in/out, fp32 accumulate.
//
// m201-style 8-phase schedule in plain HIP:
//  - 512 thr / 8 waves (2M x 4N), BK=64, 128 KiB LDS double-buffer.
//  - per K-tile, 4 phases: {ds_read A-quadrant (4x b128; +8 B reads at q0)
//    | stage 1 half-tile (2x global_load_lds) | s_barrier | lgkmcnt(0) |
//    setprio(1) 16 MFMA setprio(0) | [vmcnt(6) at q3] | s_barrier}.
//  - counted vmcnt, never 0 in steady state: loads run 1.5 tiles ahead
//    via half-tile region recycling (B halves of buf b are free after
//    tile-t phase0, A-half0 after phase1 -> tile t+2's loads into buf b
//    can be issued at phases 1..3 of tile t). Single wait per tile:
//    vmcnt(6) at phase 3 (= 3 half-tiles of t+2 issued after the last
//    load of t+1).
//  - T2 XOR swizzle (chunk ^= row&7): applied on the per-lane GLOBAL
//    source address (LDS dest must stay linear for global_load_lds) and
//    on the ds_read byte address. Kills the 8-way conflict of 128B-row
//    b128 reads (each quad group spreads over all 8 16B slots).
//  - A staging interleave: LDS A-inst q holds rows {q*32..+31} u
//    {128+q*32..+31} so phase-q rows for BOTH M-waves live in one
//    staging instruction -> per-tile vmcnt(6) is sufficient.

#define BM 256
#define BN 256

__global__ __launch_bounds__(512) void gemm_bias_elu_kernel(
    const u16* __restrict__ A_base, long a_estride,
    const u16* __restrict__ Wt_base, long w_estride,
    const float* __restrict__ bias_base, long b_estride,
    u16* __restrict__ C_base, long c_estride,
    int M, int N, int K, int ntn, int ntm) {
  // bijective XCD-aware swizzle (m204): works for any grid size
  int nwg = gridDim.x;
  int orig = blockIdx.x;
  int xcd = orig & 7;
  int q8 = nwg >> 3, r8 = nwg & 7;
  int wid = (xcd < r8 ? xcd * (q8 + 1) : r8 * (q8 + 1) + (xcd - r8) * q8) +
            (orig >> 3);
  int tpe = ntn * ntm;
  int e = wid / tpe;
  int rem = wid - e * tpe;
  int mt = rem / ntn;       // m-tile outer
  int nt = rem - mt * ntn;  // n-tile inner -> A-tile reuse in time
  int m0 = mt * BM;
  int n0 = nt * BN;

  const u16* A = A_base + (long)e * a_estride;
  const u16* Wt = Wt_base + (long)e * w_estride;
  const float* bias = bias_base + (long)e * b_estride;
  u16* C = C_base + (long)e * c_estride;

  // [buf][A 32KB | B 32KB] x2 = 128 KiB
  __shared__ __align__(16) unsigned char smem[131072];

  int tid = threadIdx.x;
  int lane = tid & 63;
  int w = tid >> 6;   // 0..7
  int wm = w >> 2;    // 0..1  (128 rows each)
  int wn = w & 3;     // 0..3  (64 cols each)
  int col = lane & 15;
  int quad = lane >> 4;

  // ---- staging addresses (pre-swizzled global source, linear LDS) ----
  int sLog = (tid & 7) ^ ((tid >> 3) & 7);          // logical K-chunk
  int rA0 = ((tid >> 3) & 31) + ((tid & 256) ? 128 : 0);
  const u16* gA = A + (long)(m0 + rA0) * K + sLog * 8;
  const u16* gB = Wt + (long)(n0 + (tid >> 3)) * K + sLog * 8;
  int dstOff = tid * 16;  // bytes

  // ---- ds_read addresses (swizzled) ----
  int xo0 = (quad ^ (col & 7)) * 16;           // kk=0 chunk byte; kk=1: ^64
  int aBase = (wm * 32 + col) * 128;           // + q*8192 + f*2048
  int bBase = (wn * 64 + col) * 128;           // + 32768 + j*2048

  floatx4 acc[8][4] = {};
  bf16x8 bf[4][2];
  int NT = K >> 6;

  auto stageA = [&](int b, int q, int k0) {
    gld_lds16(gA + (long)(q * 32) * K + k0,
              (u16*)(smem + b * 65536 + q * 8192 + dstOff));
  };
  auto stageB = [&](int b, int i, int k0) {
    gld_lds16(gB + (long)(i * 64) * K + k0,
              (u16*)(smem + b * 65536 + 32768 + i * 8192 + dstOff));
  };
  auto ldA = [&](int b, int q, int f, int kk) -> bf16x8 {
    return ld_bf8((const u16*)(smem + b * 65536 + q * 8192 + aBase +
                               f * 2048 + (xo0 ^ (kk * 64))));
  };
  auto ldB = [&](int b, int j, int kk) -> bf16x8 {
    return ld_bf8((const u16*)(smem + b * 65536 + 32768 + bBase + j * 2048 +
                               (xo0 ^ (kk * 64))));
  };

  // ---- prologue: tile0 fully + tile1's B-halves and A-half0 ----
  stageB(0, 0, 0); stageB(0, 1, 0); stageB(0, 2, 0); stageB(0, 3, 0);
  stageA(0, 0, 0); stageA(0, 1, 0); stageA(0, 2, 0); stageA(0, 3, 0);
  if (NT > 1) {
    stageB(1, 0, 64); stageB(1, 1, 64); stageB(1, 2, 64); stageB(1, 3, 64);
    stageA(1, 0, 64); stageA(1, 1, 64);
    asm volatile("s_waitcnt vmcnt(6)" ::: "memory");
  } else {
    asm volatile("s_waitcnt vmcnt(0)" ::: "memory");
  }
  __builtin_amdgcn_s_barrier();

  for (int t = 0; t < NT; ++t) {
    int b = t & 1;
    int nb = b ^ 1;
    int kc1 = (t + 1) << 6;
    int kc2 = (t + 2) << 6;
    bool s1 = (t + 1 < NT);
    bool s2 = (t + 2 < NT);

#pragma unroll
    for (int q = 0; q < 4; ++q) {
      bf16x8 a00 = ldA(b, q, 0, 0);
      bf16x8 a01 = ldA(b, q, 0, 1);
      bf16x8 a10 = ldA(b, q, 1, 0);
      bf16x8 a11 = ldA(b, q, 1, 1);
      if (q == 0) {
#pragma unroll
        for (int j = 0; j < 4; ++j) {
          bf[j][0] = ldB(b, j, 0);
          bf[j][1] = ldB(b, j, 1);
        }
        if (s1) { stageA(nb, 2, kc1); stageA(nb, 3, kc1); }
      } else if (q == 1) {
        if (s2) { stageB(b, 0, kc2); stageB(b, 1, kc2); }
      } else if (q == 2) {
        if (s2) { stageB(b, 2, kc2); stageB(b, 3, kc2); }
      } else {
        if (s2) { stageA(b, 0, kc2); stageA(b, 1, kc2); }
      }
      __builtin_amdgcn_s_barrier();
      asm volatile("s_waitcnt lgkmcnt(0)" ::: "memory");
      __builtin_amdgcn_sched_barrier(0);
      __builtin_amdgcn_s_setprio(1);
#pragma unroll
      for (int j = 0; j < 4; ++j) {
        acc[2 * q][j] = __builtin_amdgcn_mfma_f32_16x16x32_bf16(
            bf[j][0], a00, acc[2 * q][j], 0, 0, 0);
        acc[2 * q][j] = __builtin_amdgcn_mfma_f32_16x16x32_bf16(
            bf[j][1], a01, acc[2 * q][j], 0, 0, 0);
        acc[2 * q + 1][j] = __builtin_amdgcn_mfma_f32_16x16x32_bf16(
            bf[j][0], a10, acc[2 * q + 1][j], 0, 0, 0);
        acc[2 * q + 1][j] = __builtin_amdgcn_mfma_f32_16x16x32_bf16(
            bf[j][1], a11, acc[2 * q + 1][j], 0, 0, 0);
      }
      __builtin_amdgcn_s_setprio(0);
      if (q == 3 && s1) {
        if (s2) asm volatile("s_waitcnt vmcnt(6)" ::: "memory");
        else    asm volatile("s_waitcnt vmcnt(0)" ::: "memory");
      }
      __builtin_amdgcn_s_barrier();
    }
  }

  // epilogue: m = m0+wm*128+i*16+col, n = n0+wn*64+j*16+quad*4+[0..3]
#pragma unroll
  for (int j = 0; j < 4; ++j) {
    int nn = n0 + wn * 64 + j * 16 + quad * 4;
    float4 b4 = *reinterpret_cast<const float4*>(&bias[nn]);
#pragma unroll
    for (int i = 0; i < 8; ++i) {
      int m = m0 + wm * 128 + i * 16 + col;
      u16x4 o;
      o.x = f2bf(elu1(acc[i][j][0] + b4.x));
      o.y = f2bf(elu1(acc[i][j][1] + b4.y));
      o.z = f2bf(elu1(acc[i][j][2] + b4.z));
      o.w = f2bf(elu1(acc[i][j][3] + b4.w));
      *reinterpret_cast<u16x4*>(&C[(long)m * N + nn]) = o;
    }
  }
}

// ---------------- fused L4: gate + softmax + expert heads + combine -------
__global__ __launch_bounds__(256) void final_combine_kernel(
    const u16* __restrict__ h3, const u16* __restrict__ W4t,
    const u16* __restrict__ gW4t, const float* __restrict__ eb4,
    const float* __restrict__ gb4, float* __restrict__ out) {
  const int H3 = 256;
  int tid = threadIdx.x;
  int lane = tid & 63;
  int w = tid >> 6;  // wave 0..3
  int col = lane & 15;
  int quad = lane >> 4;
  int r0 = blockIdx.x * 16;

  // ---- gate logits (every wave, same 16 rows) ----
  floatx4 g0 = {}, g1 = {};
  const u16* h3g = h3 + (long)E_EXP * B_SZ * H3;
#pragma unroll
  for (int k0 = 0; k0 < 256; k0 += 32) {
    bf16x8 a = ld_bf8(&h3g[(long)(r0 + col) * H3 + k0 + quad * 8]);
    bf16x8 b0 = ld_bf8(&gW4t[(long)col * H3 + k0 + quad * 8]);
    bf16x8 b1 = ld_bf8(&gW4t[(long)(16 + col) * H3 + k0 + quad * 8]);
    g0 = __builtin_amdgcn_mfma_f32_16x16x32_bf16(a, b0, g0, 0, 0, 0);
    g1 = __builtin_amdgcn_mfma_f32_16x16x32_bf16(a, b1, g1, 0, 0, 0);
  }

  // ---- softmax over 20 logits per row ----
  float w0[4], w1[4];
  float gbc0 = gb4[col];
  float gbc1 = (col < 4) ? gb4[16 + col] : 0.f;
#pragma unroll
  for (int r = 0; r < 4; ++r) {
    float v0 = g0[r] + gbc0;
    float v1 = (col < 4) ? (g1[r] + gbc1) : -1e30f;
    float m = fmaxf(v0, v1);
#pragma unroll
    for (int s = 1; s < 16; s <<= 1) m = fmaxf(m, __shfl_xor(m, s, 64));
    float e0 = __expf(v0 - m);
    float e1 = (col < 4) ? __expf(v1 - m) : 0.f;
    float ssum = e0 + e1;
#pragma unroll
    for (int s = 1; s < 16; s <<= 1) ssum += __shfl_xor(ssum, s, 64);
    w0[r] = e0 / ssum;
    w1[r] = e1 / ssum;
  }

  // ---- this wave's experts: w, w+4, w+8, w+12, w+16 ----
  floatx4 o0 = {}, o1 = {};
  for (int e = w; e < E_EXP; e += 4) {
    floatx4 a0 = {}, a1 = {};
    const u16* he = h3 + (long)e * B_SZ * H3;
    const u16* we = W4t + (long)e * 32 * H3;
#pragma unroll
    for (int k0 = 0; k0 < 256; k0 += 32) {
      bf16x8 a = ld_bf8(&he[(long)(r0 + col) * H3 + k0 + quad * 8]);
      bf16x8 b0 = ld_bf8(&we[(long)col * H3 + k0 + quad * 8]);
      bf16x8 b1 = ld_bf8(&we[(long)(16 + col) * H3 + k0 + quad * 8]);
      a0 = __builtin_amdgcn_mfma_f32_16x16x32_bf16(a, b0, a0, 0, 0, 0);
      a1 = __builtin_amdgcn_mfma_f32_16x16x32_bf16(a, b1, a1, 0, 0, 0);
    }
    float be0 = eb4[e * 32 + col];
    float be1 = eb4[e * 32 + 16 + col];
    int src = (lane & 48) + (e & 15);
#pragma unroll
    for (int r = 0; r < 4; ++r) {
      float wr = __shfl((e < 16) ? w0[r] : w1[r], src, 64);
      o0[r] += wr * (a0[r] + be0);
      o1[r] += wr * (a1[r] + be1);
    }
  }

  // ---- cross-wave reduce in LDS ----
  __shared__ float red[3][64][8];
  if (w > 0) {
#pragma unroll
    for (int r = 0; r < 4; ++r) {
      red[w - 1][lane][r] = o0[r];
      red[w - 1][lane][4 + r] = o1[r];
    }
  }
  __syncthreads();
  if (w == 0) {
#pragma unroll
    for (int ww = 0; ww < 3; ++ww)
#pragma unroll
      for (int r = 0; r < 4; ++r) {
        o0[r] += red[ww][lane][r];
        o1[r] += red[ww][lane][4 + r];
      }
#pragma unroll
    for (int r = 0; r < 4; ++r) {
      int row = r0 + quad * 4 + r;
      out[(long)row * 32 + col] = o0[r];
      out[(long)row * 32 + 16 + col] = o1[r];
    }
  }
}

// ---------------- host launch ----------------

static inline size_t align256(size_t x) { return (x + 255) & ~(size_t)255; }

extern "C" void kernel_launch(void* const* d_in, const int* in_sizes, int n_in,
                              void* d_out, int out_size, void* d_ws,
                              size_t ws_size, hipStream_t stream) {
  const float* obs = (const float*)d_in[0];
  const float* eW1 = (const float*)d_in[1];
  const float* eb1 = (const float*)d_in[2];
  const float* eW2 = (const float*)d_in[3];
  const float* eb2 = (const float*)d_in[4];
  const float* eW3 = (const float*)d_in[5];
  const float* eb3 = (const float*)d_in[6];
  const float* eW4 = (const float*)d_in[7];
  const float* eb4 = (const float*)d_in[8];
  const float* gW1 = (const float*)d_in[9];
  const float* gb1 = (const float*)d_in[10];
  const float* gW2 = (const float*)d_in[11];
  const float* gb2 = (const float*)d_in[12];
  const float* gW3 = (const float*)d_in[13];
  const float* gb3 = (const float*)d_in[14];
  const float* gW4 = (const float*)d_in[15];
  const float* gb4 = (const float*)d_in[16];
  float* out = (float*)d_out;
  char* ws = (char*)d_ws;

  // fixed workspace region
  size_t off = 0;
  size_t OFF_OBS = off;  off = align256(off + (size_t)B_SZ * 512 * 2);
  size_t OFF_W1T = off;  off = align256(off + (size_t)NE * 1024 * 512 * 2);
  size_t OFF_W2T = off;  off = align256(off + (size_t)NE * 512 * 1024 * 2);
  size_t OFF_W3T = off;  off = align256(off + (size_t)NE * 256 * 512 * 2);
  size_t OFF_W4T = off;  off = align256(off + (size_t)E_EXP * 32 * 256 * 2);
  size_t OFF_GW4T = off; off = align256(off + (size_t)32 * 256 * 2);
  size_t OFF_B1 = off;   off = align256(off + (size_t)NE * 1024 * 4);
  size_t OFF_B2 = off;   off = align256(off + (size_t)NE * 512 * 4);
  size_t OFF_B3 = off;   off = align256(off + (size_t)NE * 256 * 4);
  size_t OFF_H3 = off;   off = align256(off + (size_t)NE * B_SZ * 256 * 2);

  // adaptive batch-chunked h1/h2: every dispatch covers all 21 experts
  int chunk = B_SZ;
  size_t OFF_H1 = off;
  while (chunk > 512) {
    size_t need = (size_t)NE * chunk * 1024 * 2 + (size_t)NE * chunk * 512 * 2;
    if (OFF_H1 + need <= ws_size) break;
    chunk >>= 1;
  }
  size_t OFF_H2 = align256(OFF_H1 + (size_t)NE * chunk * 1024 * 2);

  u16* obs_bf = (u16*)(ws + OFF_OBS);
  u16* W1t = (u16*)(ws + OFF_W1T);
  u16* W2t = (u16*)(ws + OFF_W2T);
  u16* W3t = (u16*)(ws + OFF_W3T);
  u16* W4t = (u16*)(ws + OFF_W4T);
  u16* gW4t = (u16*)(ws + OFF_GW4T);
  float* b1 = (float*)(ws + OFF_B1);
  float* b2 = (float*)(ws + OFF_B2);
  float* b3 = (float*)(ws + OFF_B3);
  u16* h3 = (u16*)(ws + OFF_H3);
  u16* h1 = (u16*)(ws + OFF_H1);
  u16* h2 = (u16*)(ws + OFF_H2);

  // --- prep: obs convert + bias concat (1), all transposes (1) ---
  prep_small_kernel<<<2048 + (NE * 1792 + 255) / 256, 256, 0, stream>>>(
      obs, obs_bf, eb1, gb1, eb2, gb2, eb3, gb3, b1, b2, b3);
  transpose_all_kernel<<<TRANS_BLOCKS, 256, 0, stream>>>(
      eW1, gW1, eW2, gW2, eW3, gW3, eW4, gW4, W1t, W2t, W3t, W4t, gW4t);

  int ntm = chunk / BM;  // BM = 256
  // --- trunk layers 1..3, batch-chunked, 8-phase 256x256 grouped GEMM ---
  for (int bc = 0; bc < B_SZ; bc += chunk) {
    gemm_bias_elu_kernel<<<NE * 4 * ntm, 512, 0, stream>>>(
        obs_bf + (size_t)bc * 512, 0L,
        W1t, (long)1024 * 512,
        b1, 1024L,
        h1, (long)chunk * 1024, chunk, 1024, 512, 4, ntm);
    gemm_bias_elu_kernel<<<NE * 2 * ntm, 512, 0, stream>>>(
        h1, (long)chunk * 1024,
        W2t, (long)512 * 1024,
        b2, 512L,
        h2, (long)chunk * 512, chunk, 512, 1024, 2, ntm);
    gemm_bias_elu_kernel<<<NE * 1 * ntm, 512, 0, stream>>>(
        h2, (long)chunk * 512,
        W3t, (long)256 * 512,
        b3, 256L,
        h3 + (size_t)bc * 256, (long)B_SZ * 256, chunk, 256, 512, 1, ntm);
  }

  // --- fused layer-4 + softmax + combine ---
  final_combine_kernel<<<B_SZ / 16, 256, 0, stream>>>(h3, W4t, gW4t, eb4, gb4,
                                                      out);
}

// Round 2
// 521.414 us; speedup vs baseline: 1.0124x; 1.0124x over previous
//
#include <hip/hip_runtime.h>

#define B_SZ 4096
#define E_EXP 20
#define NE 21  // 20 experts + gate share the trunk

typedef unsigned short u16;
typedef __bf16 bf16x8 __attribute__((ext_vector_type(8)));
typedef u16 u16x8 __attribute__((ext_vector_type(8)));
typedef u16 u16x4 __attribute__((ext_vector_type(4)));
typedef float floatx4 __attribute__((ext_vector_type(4)));

static __device__ __forceinline__ u16 f2bf(float f) {
  unsigned u = __builtin_bit_cast(unsigned, f);
  u += 0x7fffu + ((u >> 16) & 1u);  // RNE
  return (u16)(u >> 16);
}

static __device__ __forceinline__ float elu1(float v) {
  return v > 0.f ? v : (__expf(v) - 1.f);
}

static __device__ __forceinline__ bf16x8 ld_bf8(const u16* p) {
  u16x8 v = *reinterpret_cast<const u16x8*>(p);
  return __builtin_bit_cast(bf16x8, v);
}

// async global->LDS DMA, 16B per lane. LDS dest is wave-uniform base +
// lane*16 — lds ptr must be linear in thread order (no padding!).
static __device__ __forceinline__ void gld_lds16(const u16* g, u16* l) {
  __builtin_amdgcn_global_load_lds(
      (const __attribute__((address_space(1))) unsigned int*)g,
      (__attribute__((address_space(3))) unsigned int*)l, 16, 0, 0);
}

// Opaque barrier: the compiler's waitcnt pass force-drains vmcnt before a
// visible S_BARRIER when LDS-DMA (global_load_lds) is outstanding — which
// destroyed the counted-vmcnt pipeline in R1 (MfmaUtil 16%). An inline-asm
// s_barrier is invisible to that pass; our explicit vmcnt(6)/lgkmcnt(0)
// remain the only waits in the loop.
#define BAR() asm volatile("s_barrier" ::: "memory")

// ---------------- prep: obs convert + bias concat, one dispatch ----------

__global__ void prep_small_kernel(
    const float* __restrict__ obs, u16* __restrict__ obs_bf,
    const float* __restrict__ eb1, const float* __restrict__ gb1,
    const float* __restrict__ eb2, const float* __restrict__ gb2,
    const float* __restrict__ eb3, const float* __restrict__ gb3,
    float* __restrict__ b1, float* __restrict__ b2, float* __restrict__ b3) {
  int bid = blockIdx.x;
  if (bid < 2048) {  // obs: B_SZ*512 floats, 4/thread
    int i = (bid * 256 + threadIdx.x) * 4;
    float4 v = *reinterpret_cast<const float4*>(obs + i);
    u16x4 o;
    o.x = f2bf(v.x); o.y = f2bf(v.y); o.z = f2bf(v.z); o.w = f2bf(v.w);
    *reinterpret_cast<u16x4*>(obs_bf + i) = o;
  } else {
    int i = (bid - 2048) * 256 + threadIdx.x;
    const int S1 = NE * 1024, S2 = NE * 512, S3 = NE * 256;
    if (i < S1) {
      b1[i] = (i < E_EXP * 1024) ? eb1[i] : gb1[i - E_EXP * 1024];
    } else if (i < S1 + S2) {
      int j = i - S1;
      b2[j] = (j < E_EXP * 512) ? eb2[j] : gb2[j - E_EXP * 512];
    } else if (i < S1 + S2 + S3) {
      int j = i - S1 - S2;
      b3[j] = (j < E_EXP * 256) ? eb3[j] : gb3[j - E_EXP * 256];
    }
  }
}

// ---------------- all weight transposes, one job-table dispatch ----------
#define TRANS_BLOCKS 6132

__global__ __launch_bounds__(256) void transpose_all_kernel(
    const float* __restrict__ eW1, const float* __restrict__ gW1,
    const float* __restrict__ eW2, const float* __restrict__ gW2,
    const float* __restrict__ eW3, const float* __restrict__ gW3,
    const float* __restrict__ eW4, const float* __restrict__ gW4,
    u16* __restrict__ W1t, u16* __restrict__ W2t, u16* __restrict__ W3t,
    u16* __restrict__ W4t, u16* __restrict__ gW4t) {
  int f = blockIdx.x;
  const float *srcE, *srcG;
  u16* dstBase;
  int rem, K, N, Nout, kxt, tpm, nm;
  if (f < 2688) {
    rem = f;        srcE = eW1; srcG = gW1; dstBase = W1t;
    K = 512;  N = 1024; Nout = 1024; kxt = 8;  tpm = 128; nm = 20;
  } else if (f < 5376) {
    rem = f - 2688; srcE = eW2; srcG = gW2; dstBase = W2t;
    K = 1024; N = 512;  Nout = 512;  kxt = 16; tpm = 128; nm = 20;
  } else if (f < 6048) {
    rem = f - 5376; srcE = eW3; srcG = gW3; dstBase = W3t;
    K = 512;  N = 256;  Nout = 256;  kxt = 8;  tpm = 32;  nm = 20;
  } else if (f < 6128) {
    rem = f - 6048; srcE = eW4; srcG = nullptr; dstBase = W4t;
    K = 256;  N = 32;   Nout = 32;   kxt = 4;  tpm = 4;   nm = 99;
  } else {
    rem = f - 6128; srcE = gW4; srcG = nullptr; dstBase = gW4t;
    K = 256;  N = 20;   Nout = 32;   kxt = 4;  tpm = 4;   nm = 99;
  }
  int mat = rem / tpm;
  int t = rem % tpm;
  const float* src = (mat < nm) ? (srcE + (long)mat * K * N) : srcG;
  u16* dst = dstBase + (long)mat * Nout * K;
  int kbase = (t % kxt) * 64;
  int nbase = (t / kxt) * 64;

  __shared__ float tl[64][65];
  int tid = threadIdx.x;
  int kk = tid >> 4;        // 0..15
  int n4 = (tid & 15) * 4;  // 0..60
#pragma unroll
  for (int p = 0; p < 4; ++p) {
    int k = kbase + p * 16 + kk;  // always < K (grid exact)
    int n = nbase + n4;
    float4 v = make_float4(0.f, 0.f, 0.f, 0.f);
    if (n + 3 < N) {
      v = *reinterpret_cast<const float4*>(&src[(long)k * N + n]);
    } else {
      float* vp = &v.x;
      for (int j = 0; j < 4; ++j)
        if (n + j < N) vp[j] = src[(long)k * N + n + j];
    }
    tl[p * 16 + kk][n4 + 0] = v.x;
    tl[p * 16 + kk][n4 + 1] = v.y;
    tl[p * 16 + kk][n4 + 2] = v.z;
    tl[p * 16 + kk][n4 + 3] = v.w;
  }
  __syncthreads();

  int kk8 = (tid & 7) * 8;
#pragma unroll
  for (int p = 0; p < 2; ++p) {
    int ln = p * 32 + (tid >> 3);  // 0..63
    int n = nbase + ln;
    if (n < Nout) {
      u16x8 o;
#pragma unroll
      for (int j = 0; j < 8; ++j) o[j] = f2bf(tl[kk8 + j][ln]);
      *reinterpret_cast<u16x8*>(&dst[(long)n * K + kbase + kk8]) = o;
    }
  }
}

// ---------------- grouped GEMM + bias + ELU, 256x256 8-phase -------------
// C[M,N] = elu(A[M,K] @ Wt[N,K]^T + bias), bf16 in/out, fp32 accumulate.
//
// m201-style 8-phase schedule in plain HIP:
//  - 512 thr / 8 waves (2M x 4N), BK=64, 128 KiB LDS double-buffer.
//  - per K-tile, 4 phases: {ds_read A-quadrant (4x b128; +8 B reads at q0)
//    | stage 1 half-tile (2x global_load_lds) | s_barrier(asm) | lgkmcnt(0)
//    | setprio(1) 16 MFMA setprio(0) | [vmcnt(6) at q3] | s_barrier(asm)}.
//  - counted vmcnt, never 0 in steady state. Single wait per tile:
//    vmcnt(6) at phase 3 (= 3 half-tiles of t+2 issued after the last
//    load of t+1). Barriers are OPAQUE asm so the compiler cannot insert
//    its own vmcnt(0) drain for outstanding LDS-DMA (R1 post-mortem).
//  - WAR discipline: a stage at phase q only overwrites LDS regions whose
//    last ds_reads were drained (lgkmcnt(0)) before phase q-1's trailing
//    barrier, so the opaque barriers preserve correctness.
//  - T2 XOR swizzle (chunk ^= row&7) on the per-lane GLOBAL source and on
//    the ds_read byte address; LDS dest stays linear (rule #21).

#define BM 256
#define BN 256

__global__ __launch_bounds__(512) void gemm_bias_elu_kernel(
    const u16* __restrict__ A_base, long a_estride,
    const u16* __restrict__ Wt_base, long w_estride,
    const float* __restrict__ bias_base, long b_estride,
    u16* __restrict__ C_base, long c_estride,
    int M, int N, int K, int ntn, int ntm) {
  // bijective XCD-aware swizzle (m204): works for any grid size
  int nwg = gridDim.x;
  int orig = blockIdx.x;
  int xcd = orig & 7;
  int q8 = nwg >> 3, r8 = nwg & 7;
  int wid = (xcd < r8 ? xcd * (q8 + 1) : r8 * (q8 + 1) + (xcd - r8) * q8) +
            (orig >> 3);
  int tpe = ntn * ntm;
  int e = wid / tpe;
  int rem = wid - e * tpe;
  int mt = rem / ntn;       // m-tile outer
  int nt = rem - mt * ntn;  // n-tile inner -> A-tile reuse in time
  int m0 = mt * BM;
  int n0 = nt * BN;

  const u16* A = A_base + (long)e * a_estride;
  const u16* Wt = Wt_base + (long)e * w_estride;
  const float* bias = bias_base + (long)e * b_estride;
  u16* C = C_base + (long)e * c_estride;

  // [buf][A 32KB | B 32KB] x2 = 128 KiB
  __shared__ __align__(16) unsigned char smem[131072];

  int tid = threadIdx.x;
  int lane = tid & 63;
  int w = tid >> 6;   // 0..7
  int wm = w >> 2;    // 0..1  (128 rows each)
  int wn = w & 3;     // 0..3  (64 cols each)
  int col = lane & 15;
  int quad = lane >> 4;

  // ---- staging addresses (pre-swizzled global source, linear LDS) ----
  int sLog = (tid & 7) ^ ((tid >> 3) & 7);          // logical K-chunk
  int rA0 = ((tid >> 3) & 31) + ((tid & 256) ? 128 : 0);
  const u16* gA = A + (long)(m0 + rA0) * K + sLog * 8;
  const u16* gB = Wt + (long)(n0 + (tid >> 3)) * K + sLog * 8;
  int dstOff = tid * 16;  // bytes

  // ---- ds_read addresses (swizzled) ----
  int xo0 = (quad ^ (col & 7)) * 16;           // kk=0 chunk byte; kk=1: ^64
  int aBase = (wm * 32 + col) * 128;           // + q*8192 + f*2048
  int bBase = (wn * 64 + col) * 128;           // + 32768 + j*2048

  floatx4 acc[8][4] = {};
  bf16x8 bf[4][2];
  int NT = K >> 6;

  auto stageA = [&](int b, int q, int k0) {
    gld_lds16(gA + (long)(q * 32) * K + k0,
              (u16*)(smem + b * 65536 + q * 8192 + dstOff));
  };
  auto stageB = [&](int b, int i, int k0) {
    gld_lds16(gB + (long)(i * 64) * K + k0,
              (u16*)(smem + b * 65536 + 32768 + i * 8192 + dstOff));
  };
  auto ldA = [&](int b, int q, int f, int kk) -> bf16x8 {
    return ld_bf8((const u16*)(smem + b * 65536 + q * 8192 + aBase +
                               f * 2048 + (xo0 ^ (kk * 64))));
  };
  auto ldB = [&](int b, int j, int kk) -> bf16x8 {
    return ld_bf8((const u16*)(smem + b * 65536 + 32768 + bBase + j * 2048 +
                               (xo0 ^ (kk * 64))));
  };

  // ---- prologue: tile0 fully + tile1's B-halves and A-half0 ----
  stageB(0, 0, 0); stageB(0, 1, 0); stageB(0, 2, 0); stageB(0, 3, 0);
  stageA(0, 0, 0); stageA(0, 1, 0); stageA(0, 2, 0); stageA(0, 3, 0);
  if (NT > 1) {
    stageB(1, 0, 64); stageB(1, 1, 64); stageB(1, 2, 64); stageB(1, 3, 64);
    stageA(1, 0, 64); stageA(1, 1, 64);
    asm volatile("s_waitcnt vmcnt(6)" ::: "memory");
  } else {
    asm volatile("s_waitcnt vmcnt(0)" ::: "memory");
  }
  BAR();

  for (int t = 0; t < NT; ++t) {
    int b = t & 1;
    int nb = b ^ 1;
    int kc1 = (t + 1) << 6;
    int kc2 = (t + 2) << 6;
    bool s1 = (t + 1 < NT);
    bool s2 = (t + 2 < NT);

#pragma unroll
    for (int q = 0; q < 4; ++q) {
      bf16x8 a00 = ldA(b, q, 0, 0);
      bf16x8 a01 = ldA(b, q, 0, 1);
      bf16x8 a10 = ldA(b, q, 1, 0);
      bf16x8 a11 = ldA(b, q, 1, 1);
      if (q == 0) {
#pragma unroll
        for (int j = 0; j < 4; ++j) {
          bf[j][0] = ldB(b, j, 0);
          bf[j][1] = ldB(b, j, 1);
        }
        if (s1) { stageA(nb, 2, kc1); stageA(nb, 3, kc1); }
      } else if (q == 1) {
        if (s2) { stageB(b, 0, kc2); stageB(b, 1, kc2); }
      } else if (q == 2) {
        if (s2) { stageB(b, 2, kc2); stageB(b, 3, kc2); }
      } else {
        if (s2) { stageA(b, 0, kc2); stageA(b, 1, kc2); }
      }
      BAR();
      asm volatile("s_waitcnt lgkmcnt(0)" ::: "memory");
      __builtin_amdgcn_sched_barrier(0);
      __builtin_amdgcn_s_setprio(1);
#pragma unroll
      for (int j = 0; j < 4; ++j) {
        acc[2 * q][j] = __builtin_amdgcn_mfma_f32_16x16x32_bf16(
            bf[j][0], a00, acc[2 * q][j], 0, 0, 0);
        acc[2 * q][j] = __builtin_amdgcn_mfma_f32_16x16x32_bf16(
            bf[j][1], a01, acc[2 * q][j], 0, 0, 0);
        acc[2 * q + 1][j] = __builtin_amdgcn_mfma_f32_16x16x32_bf16(
            bf[j][0], a10, acc[2 * q + 1][j], 0, 0, 0);
        acc[2 * q + 1][j] = __builtin_amdgcn_mfma_f32_16x16x32_bf16(
            bf[j][1], a11, acc[2 * q + 1][j], 0, 0, 0);
      }
      __builtin_amdgcn_s_setprio(0);
      if (q == 3 && s1) {
        if (s2) asm volatile("s_waitcnt vmcnt(6)" ::: "memory");
        else    asm volatile("s_waitcnt vmcnt(0)" ::: "memory");
      }
      BAR();
    }
  }

  // epilogue: m = m0+wm*128+i*16+col, n = n0+wn*64+j*16+quad*4+[0..3]
  // i-outer / j-inner: the 4 stores covering a row's 128B line are
  // back-to-back, so L2 merges the line before eviction (R1 had 2x
  // write amplification from j-outer partial-dirty evictions).
  float4 b4[4];
#pragma unroll
  for (int j = 0; j < 4; ++j)
    b4[j] = *reinterpret_cast<const float4*>(
        &bias[n0 + wn * 64 + j * 16 + quad * 4]);
#pragma unroll
  for (int i = 0; i < 8; ++i) {
    int m = m0 + wm * 128 + i * 16 + col;
#pragma unroll
    for (int j = 0; j < 4; ++j) {
      int nn = n0 + wn * 64 + j * 16 + quad * 4;
      u16x4 o;
      o.x = f2bf(elu1(acc[i][j][0] + b4[j].x));
      o.y = f2bf(elu1(acc[i][j][1] + b4[j].y));
      o.z = f2bf(elu1(acc[i][j][2] + b4[j].z));
      o.w = f2bf(elu1(acc[i][j][3] + b4[j].w));
      *reinterpret_cast<u16x4*>(&C[(long)m * N + nn]) = o;
    }
  }
}

// ---------------- fused L4: gate + softmax + expert heads + combine -------
__global__ __launch_bounds__(256) void final_combine_kernel(
    const u16* __restrict__ h3, const u16* __restrict__ W4t,
    const u16* __restrict__ gW4t, const float* __restrict__ eb4,
    const float* __restrict__ gb4, float* __restrict__ out) {
  const int H3 = 256;
  int tid = threadIdx.x;
  int lane = tid & 63;
  int w = tid >> 6;  // wave 0..3
  int col = lane & 15;
  int quad = lane >> 4;
  int r0 = blockIdx.x * 16;

  // ---- gate logits (every wave, same 16 rows) ----
  floatx4 g0 = {}, g1 = {};
  const u16* h3g = h3 + (long)E_EXP * B_SZ * H3;
#pragma unroll
  for (int k0 = 0; k0 < 256; k0 += 32) {
    bf16x8 a = ld_bf8(&h3g[(long)(r0 + col) * H3 + k0 + quad * 8]);
    bf16x8 b0 = ld_bf8(&gW4t[(long)col * H3 + k0 + quad * 8]);
    bf16x8 b1 = ld_bf8(&gW4t[(long)(16 + col) * H3 + k0 + quad * 8]);
    g0 = __builtin_amdgcn_mfma_f32_16x16x32_bf16(a, b0, g0, 0, 0, 0);
    g1 = __builtin_amdgcn_mfma_f32_16x16x32_bf16(a, b1, g1, 0, 0, 0);
  }

  // ---- softmax over 20 logits per row ----
  float w0[4], w1[4];
  float gbc0 = gb4[col];
  float gbc1 = (col < 4) ? gb4[16 + col] : 0.f;
#pragma unroll
  for (int r = 0; r < 4; ++r) {
    float v0 = g0[r] + gbc0;
    float v1 = (col < 4) ? (g1[r] + gbc1) : -1e30f;
    float m = fmaxf(v0, v1);
#pragma unroll
    for (int s = 1; s < 16; s <<= 1) m = fmaxf(m, __shfl_xor(m, s, 64));
    float e0 = __expf(v0 - m);
    float e1 = (col < 4) ? __expf(v1 - m) : 0.f;
    float ssum = e0 + e1;
#pragma unroll
    for (int s = 1; s < 16; s <<= 1) ssum += __shfl_xor(ssum, s, 64);
    w0[r] = e0 / ssum;
    w1[r] = e1 / ssum;
  }

  // ---- this wave's experts: w, w+4, w+8, w+12, w+16 ----
  floatx4 o0 = {}, o1 = {};
  for (int e = w; e < E_EXP; e += 4) {
    floatx4 a0 = {}, a1 = {};
    const u16* he = h3 + (long)e * B_SZ * H3;
    const u16* we = W4t + (long)e * 32 * H3;
#pragma unroll
    for (int k0 = 0; k0 < 256; k0 += 32) {
      bf16x8 a = ld_bf8(&he[(long)(r0 + col) * H3 + k0 + quad * 8]);
      bf16x8 b0 = ld_bf8(&we[(long)col * H3 + k0 + quad * 8]);
      bf16x8 b1 = ld_bf8(&we[(long)(16 + col) * H3 + k0 + quad * 8]);
      a0 = __builtin_amdgcn_mfma_f32_16x16x32_bf16(a, b0, a0, 0, 0, 0);
      a1 = __builtin_amdgcn_mfma_f32_16x16x32_bf16(a, b1, a1, 0, 0, 0);
    }
    float be0 = eb4[e * 32 + col];
    float be1 = eb4[e * 32 + 16 + col];
    int src = (lane & 48) + (e & 15);
#pragma unroll
    for (int r = 0; r < 4; ++r) {
      float wr = __shfl((e < 16) ? w0[r] : w1[r], src, 64);
      o0[r] += wr * (a0[r] + be0);
      o1[r] += wr * (a1[r] + be1);
    }
  }

  // ---- cross-wave reduce in LDS ----
  __shared__ float red[3][64][8];
  if (w > 0) {
#pragma unroll
    for (int r = 0; r < 4; ++r) {
      red[w - 1][lane][r] = o0[r];
      red[w - 1][lane][4 + r] = o1[r];
    }
  }
  __syncthreads();
  if (w == 0) {
#pragma unroll
    for (int ww = 0; ww < 3; ++ww)
#pragma unroll
      for (int r = 0; r < 4; ++r) {
        o0[r] += red[ww][lane][r];
        o1[r] += red[ww][lane][4 + r];
      }
#pragma unroll
    for (int r = 0; r < 4; ++r) {
      int row = r0 + quad * 4 + r;
      out[(long)row * 32 + col] = o0[r];
      out[(long)row * 32 + 16 + col] = o1[r];
    }
  }
}

// ---------------- host launch ----------------

static inline size_t align256(size_t x) { return (x + 255) & ~(size_t)255; }

extern "C" void kernel_launch(void* const* d_in, const int* in_sizes, int n_in,
                              void* d_out, int out_size, void* d_ws,
                              size_t ws_size, hipStream_t stream) {
  const float* obs = (const float*)d_in[0];
  const float* eW1 = (const float*)d_in[1];
  const float* eb1 = (const float*)d_in[2];
  const float* eW2 = (const float*)d_in[3];
  const float* eb2 = (const float*)d_in[4];
  const float* eW3 = (const float*)d_in[5];
  const float* eb3 = (const float*)d_in[6];
  const float* eW4 = (const float*)d_in[7];
  const float* eb4 = (const float*)d_in[8];
  const float* gW1 = (const float*)d_in[9];
  const float* gb1 = (const float*)d_in[10];
  const float* gW2 = (const float*)d_in[11];
  const float* gb2 = (const float*)d_in[12];
  const float* gW3 = (const float*)d_in[13];
  const float* gb3 = (const float*)d_in[14];
  const float* gW4 = (const float*)d_in[15];
  const float* gb4 = (const float*)d_in[16];
  float* out = (float*)d_out;
  char* ws = (char*)d_ws;

  // fixed workspace region
  size_t off = 0;
  size_t OFF_OBS = off;  off = align256(off + (size_t)B_SZ * 512 * 2);
  size_t OFF_W1T = off;  off = align256(off + (size_t)NE * 1024 * 512 * 2);
  size_t OFF_W2T = off;  off = align256(off + (size_t)NE * 512 * 1024 * 2);
  size_t OFF_W3T = off;  off = align256(off + (size_t)NE * 256 * 512 * 2);
  size_t OFF_W4T = off;  off = align256(off + (size_t)E_EXP * 32 * 256 * 2);
  size_t OFF_GW4T = off; off = align256(off + (size_t)32 * 256 * 2);
  size_t OFF_B1 = off;   off = align256(off + (size_t)NE * 1024 * 4);
  size_t OFF_B2 = off;   off = align256(off + (size_t)NE * 512 * 4);
  size_t OFF_B3 = off;   off = align256(off + (size_t)NE * 256 * 4);
  size_t OFF_H3 = off;   off = align256(off + (size_t)NE * B_SZ * 256 * 2);

  // adaptive batch-chunked h1/h2: every dispatch covers all 21 experts
  int chunk = B_SZ;
  size_t OFF_H1 = off;
  while (chunk > 512) {
    size_t need = (size_t)NE * chunk * 1024 * 2 + (size_t)NE * chunk * 512 * 2;
    if (OFF_H1 + need <= ws_size) break;
    chunk >>= 1;
  }
  size_t OFF_H2 = align256(OFF_H1 + (size_t)NE * chunk * 1024 * 2);

  u16* obs_bf = (u16*)(ws + OFF_OBS);
  u16* W1t = (u16*)(ws + OFF_W1T);
  u16* W2t = (u16*)(ws + OFF_W2T);
  u16* W3t = (u16*)(ws + OFF_W3T);
  u16* W4t = (u16*)(ws + OFF_W4T);
  u16* gW4t = (u16*)(ws + OFF_GW4T);
  float* b1 = (float*)(ws + OFF_B1);
  float* b2 = (float*)(ws + OFF_B2);
  float* b3 = (float*)(ws + OFF_B3);
  u16* h3 = (u16*)(ws + OFF_H3);
  u16* h1 = (u16*)(ws + OFF_H1);
  u16* h2 = (u16*)(ws + OFF_H2);

  // --- prep: obs convert + bias concat (1), all transposes (1) ---
  prep_small_kernel<<<2048 + (NE * 1792 + 255) / 256, 256, 0, stream>>>(
      obs, obs_bf, eb1, gb1, eb2, gb2, eb3, gb3, b1, b2, b3);
  transpose_all_kernel<<<TRANS_BLOCKS, 256, 0, stream>>>(
      eW1, gW1, eW2, gW2, eW3, gW3, eW4, gW4, W1t, W2t, W3t, W4t, gW4t);

  int ntm = chunk / BM;  // BM = 256
  // --- trunk layers 1..3, batch-chunked, 8-phase 256x256 grouped GEMM ---
  for (int bc = 0; bc < B_SZ; bc += chunk) {
    gemm_bias_elu_kernel<<<NE * 4 * ntm, 512, 0, stream>>>(
        obs_bf + (size_t)bc * 512, 0L,
        W1t, (long)1024 * 512,
        b1, 1024L,
        h1, (long)chunk * 1024, chunk, 1024, 512, 4, ntm);
    gemm_bias_elu_kernel<<<NE * 2 * ntm, 512, 0, stream>>>(
        h1, (long)chunk * 1024,
        W2t, (long)512 * 1024,
        b2, 512L,
        h2, (long)chunk * 512, chunk, 512, 1024, 2, ntm);
    gemm_bias_elu_kernel<<<NE * 1 * ntm, 512, 0, stream>>>(
        h2, (long)chunk * 512,
        W3t, (long)256 * 512,
        b3, 256L,
        h3 + (size_t)bc * 256, (long)B_SZ * 256, chunk, 256, 512, 1, ntm);
  }

  // --- fused layer-4 + softmax + combine ---
  final_combine_kernel<<<B_SZ / 16, 256, 0, stream>>>(h3, W4t, gW4t, eb4, gb4,
                                                      out);
}

// Round 3
// 514.700 us; speedup vs baseline: 1.0256x; 1.0130x over previous
//
#include <hip/hip_runtime.h>

#define B_SZ 4096
#define E_EXP 20
#define NE 21  // 20 experts + gate share the trunk

typedef unsigned short u16;
typedef __bf16 bf16x8 __attribute__((ext_vector_type(8)));
typedef u16 u16x8 __attribute__((ext_vector_type(8)));
typedef u16 u16x4 __attribute__((ext_vector_type(4)));
typedef float floatx4 __attribute__((ext_vector_type(4)));

static __device__ __forceinline__ u16 f2bf(float f) {
  unsigned u = __builtin_bit_cast(unsigned, f);
  u += 0x7fffu + ((u >> 16) & 1u);  // RNE
  return (u16)(u >> 16);
}

static __device__ __forceinline__ float elu1(float v) {
  return v > 0.f ? v : (__expf(v) - 1.f);
}

static __device__ __forceinline__ bf16x8 ld_bf8(const u16* p) {
  u16x8 v = *reinterpret_cast<const u16x8*>(p);
  return __builtin_bit_cast(bf16x8, v);
}

// async global->LDS DMA, 16B per lane. LDS dest is wave-uniform base +
// lane*16 — lds ptr must be linear in thread order (no padding!).
static __device__ __forceinline__ void gld_lds16(const u16* g, u16* l) {
  __builtin_amdgcn_global_load_lds(
      (const __attribute__((address_space(1))) unsigned int*)g,
      (__attribute__((address_space(3))) unsigned int*)l, 16, 0, 0);
}

// Opaque barrier: keeps the waitcnt pass from draining vmcnt at barriers.
#define BAR() asm volatile("s_barrier" ::: "memory")

// OPAQUE ds_read_b128 (R2 post-mortem): LLVM's waitcnt pass treats
// global_load_lds as a VMEM op that writes LDS, and inserts a conservative
// s_waitcnt vmcnt(0) before any *visible* ds_read that may alias it —
// that drained the whole prefetch queue once per phase (8x per K-tile,
// ~1100 cyc each == the measured 3.7 us/tile). An inline-asm ds_read is
// invisible to the pass; our explicit per-tile vmcnt(6) + per-phase
// lgkmcnt(0) become the only waits. LDS address = low 32 bits of the
// generic pointer (shared aperture puts the LDS offset in the low half).
static __device__ __forceinline__ bf16x8 ds_read128(const void* p) {
  bf16x8 r;
  unsigned a = (unsigned)(size_t)p;
  asm volatile("ds_read_b128 %0, %1" : "=v"(r) : "v"(a));
  return r;
}

// ---------------- prep: obs convert + bias concat, one dispatch ----------

__global__ void prep_small_kernel(
    const float* __restrict__ obs, u16* __restrict__ obs_bf,
    const float* __restrict__ eb1, const float* __restrict__ gb1,
    const float* __restrict__ eb2, const float* __restrict__ gb2,
    const float* __restrict__ eb3, const float* __restrict__ gb3,
    float* __restrict__ b1, float* __restrict__ b2, float* __restrict__ b3) {
  int bid = blockIdx.x;
  if (bid < 2048) {  // obs: B_SZ*512 floats, 4/thread
    int i = (bid * 256 + threadIdx.x) * 4;
    float4 v = *reinterpret_cast<const float4*>(obs + i);
    u16x4 o;
    o.x = f2bf(v.x); o.y = f2bf(v.y); o.z = f2bf(v.z); o.w = f2bf(v.w);
    *reinterpret_cast<u16x4*>(obs_bf + i) = o;
  } else {
    int i = (bid - 2048) * 256 + threadIdx.x;
    const int S1 = NE * 1024, S2 = NE * 512, S3 = NE * 256;
    if (i < S1) {
      b1[i] = (i < E_EXP * 1024) ? eb1[i] : gb1[i - E_EXP * 1024];
    } else if (i < S1 + S2) {
      int j = i - S1;
      b2[j] = (j < E_EXP * 512) ? eb2[j] : gb2[j - E_EXP * 512];
    } else if (i < S1 + S2 + S3) {
      int j = i - S1 - S2;
      b3[j] = (j < E_EXP * 256) ? eb3[j] : gb3[j - E_EXP * 256];
    }
  }
}

// ---------------- all weight transposes, one job-table dispatch ----------
#define TRANS_BLOCKS 6132

__global__ __launch_bounds__(256) void transpose_all_kernel(
    const float* __restrict__ eW1, const float* __restrict__ gW1,
    const float* __restrict__ eW2, const float* __restrict__ gW2,
    const float* __restrict__ eW3, const float* __restrict__ gW3,
    const float* __restrict__ eW4, const float* __restrict__ gW4,
    u16* __restrict__ W1t, u16* __restrict__ W2t, u16* __restrict__ W3t,
    u16* __restrict__ W4t, u16* __restrict__ gW4t) {
  int f = blockIdx.x;
  const float *srcE, *srcG;
  u16* dstBase;
  int rem, K, N, Nout, kxt, tpm, nm;
  if (f < 2688) {
    rem = f;        srcE = eW1; srcG = gW1; dstBase = W1t;
    K = 512;  N = 1024; Nout = 1024; kxt = 8;  tpm = 128; nm = 20;
  } else if (f < 5376) {
    rem = f - 2688; srcE = eW2; srcG = gW2; dstBase = W2t;
    K = 1024; N = 512;  Nout = 512;  kxt = 16; tpm = 128; nm = 20;
  } else if (f < 6048) {
    rem = f - 5376; srcE = eW3; srcG = gW3; dstBase = W3t;
    K = 512;  N = 256;  Nout = 256;  kxt = 8;  tpm = 32;  nm = 20;
  } else if (f < 6128) {
    rem = f - 6048; srcE = eW4; srcG = nullptr; dstBase = W4t;
    K = 256;  N = 32;   Nout = 32;   kxt = 4;  tpm = 4;   nm = 99;
  } else {
    rem = f - 6128; srcE = gW4; srcG = nullptr; dstBase = gW4t;
    K = 256;  N = 20;   Nout = 32;   kxt = 4;  tpm = 4;   nm = 99;
  }
  int mat = rem / tpm;
  int t = rem % tpm;
  const float* src = (mat < nm) ? (srcE + (long)mat * K * N) : srcG;
  u16* dst = dstBase + (long)mat * Nout * K;
  int kbase = (t % kxt) * 64;
  int nbase = (t / kxt) * 64;

  __shared__ float tl[64][65];
  int tid = threadIdx.x;
  int kk = tid >> 4;        // 0..15
  int n4 = (tid & 15) * 4;  // 0..60
#pragma unroll
  for (int p = 0; p < 4; ++p) {
    int k = kbase + p * 16 + kk;  // always < K (grid exact)
    int n = nbase + n4;
    float4 v = make_float4(0.f, 0.f, 0.f, 0.f);
    if (n + 3 < N) {
      v = *reinterpret_cast<const float4*>(&src[(long)k * N + n]);
    } else {
      float* vp = &v.x;
      for (int j = 0; j < 4; ++j)
        if (n + j < N) vp[j] = src[(long)k * N + n + j];
    }
    tl[p * 16 + kk][n4 + 0] = v.x;
    tl[p * 16 + kk][n4 + 1] = v.y;
    tl[p * 16 + kk][n4 + 2] = v.z;
    tl[p * 16 + kk][n4 + 3] = v.w;
  }
  __syncthreads();

  int kk8 = (tid & 7) * 8;
#pragma unroll
  for (int p = 0; p < 2; ++p) {
    int ln = p * 32 + (tid >> 3);  // 0..63
    int n = nbase + ln;
    if (n < Nout) {
      u16x8 o;
#pragma unroll
      for (int j = 0; j < 8; ++j) o[j] = f2bf(tl[kk8 + j][ln]);
      *reinterpret_cast<u16x8*>(&dst[(long)n * K + kbase + kk8]) = o;
    }
  }
}

// ---------------- grouped GEMM + bias + ELU, 256x256 8-phase -------------
// C[M,N] = elu(A[M,K] @ Wt[N,K]^T + bias), bf16 in/out, fp32 accumulate.
//
// m201-style 8-phase schedule, fully manual sync (opaque barriers AND
// opaque ds_reads — see BAR()/ds_read128 comments):
//  - 512 thr / 8 waves (2M x 4N), BK=64, 128 KiB LDS double-buffer.
//  - per K-tile, 4 phases: {12x/4x asm ds_read_b128 | stage half-tile
//    (2x global_load_lds) | s_barrier | lgkmcnt(0)+sched_barrier |
//    setprio(1) 16 MFMA setprio(0) | [vmcnt(6) at q3] | s_barrier}.
//  - RAW: per-wave vmcnt(6) at q3 + barrier makes tile t+1's DMA visible.
//  - WAR: stage at phase q only overwrites regions whose ds_reads all
//    waves drained (lgkmcnt(0)) before phase q-1's trailing barrier.
//  - WAW: vmcnt retires in order.
//  - T2 XOR swizzle (chunk ^= row&7) on the per-lane GLOBAL source and on
//    the ds_read byte address; LDS dest stays linear (rule #21).

#define BM 256
#define BN 256

__global__ __launch_bounds__(512) void gemm_bias_elu_kernel(
    const u16* __restrict__ A_base, long a_estride,
    const u16* __restrict__ Wt_base, long w_estride,
    const float* __restrict__ bias_base, long b_estride,
    u16* __restrict__ C_base, long c_estride,
    int M, int N, int K, int ntn, int ntm) {
  // bijective XCD-aware swizzle (m204): works for any grid size
  int nwg = gridDim.x;
  int orig = blockIdx.x;
  int xcd = orig & 7;
  int q8 = nwg >> 3, r8 = nwg & 7;
  int wid = (xcd < r8 ? xcd * (q8 + 1) : r8 * (q8 + 1) + (xcd - r8) * q8) +
            (orig >> 3);
  int tpe = ntn * ntm;
  int e = wid / tpe;
  int rem = wid - e * tpe;
  int mt = rem / ntn;       // m-tile outer
  int nt = rem - mt * ntn;  // n-tile inner -> A-tile reuse in time
  int m0 = mt * BM;
  int n0 = nt * BN;

  const u16* A = A_base + (long)e * a_estride;
  const u16* Wt = Wt_base + (long)e * w_estride;
  const float* bias = bias_base + (long)e * b_estride;
  u16* C = C_base + (long)e * c_estride;

  // [buf][A 32KB | B 32KB] x2 = 128 KiB
  __shared__ __align__(16) unsigned char smem[131072];

  int tid = threadIdx.x;
  int lane = tid & 63;
  int w = tid >> 6;   // 0..7
  int wm = w >> 2;    // 0..1  (128 rows each)
  int wn = w & 3;     // 0..3  (64 cols each)
  int col = lane & 15;
  int quad = lane >> 4;

  // ---- staging addresses (pre-swizzled global source, linear LDS) ----
  int sLog = (tid & 7) ^ ((tid >> 3) & 7);          // logical K-chunk
  int rA0 = ((tid >> 3) & 31) + ((tid & 256) ? 128 : 0);
  const u16* gA = A + (long)(m0 + rA0) * K + sLog * 8;
  const u16* gB = Wt + (long)(n0 + (tid >> 3)) * K + sLog * 8;
  int dstOff = tid * 16;  // bytes

  // ---- ds_read addresses (swizzled) ----
  int xo0 = (quad ^ (col & 7)) * 16;           // kk=0 chunk byte; kk=1: ^64
  int aBase = (wm * 32 + col) * 128;           // + q*8192 + f*2048
  int bBase = (wn * 64 + col) * 128;           // + 32768 + j*2048

  floatx4 acc[8][4] = {};
  bf16x8 bf[4][2];
  int NT = K >> 6;

  auto stageA = [&](int b, int q, int k0) {
    gld_lds16(gA + (long)(q * 32) * K + k0,
              (u16*)(smem + b * 65536 + q * 8192 + dstOff));
  };
  auto stageB = [&](int b, int i, int k0) {
    gld_lds16(gB + (long)(i * 64) * K + k0,
              (u16*)(smem + b * 65536 + 32768 + i * 8192 + dstOff));
  };
  auto ldA = [&](int b, int q, int f, int kk) -> bf16x8 {
    return ds_read128(smem + b * 65536 + q * 8192 + aBase + f * 2048 +
                      (xo0 ^ (kk * 64)));
  };
  auto ldB = [&](int b, int j, int kk) -> bf16x8 {
    return ds_read128(smem + b * 65536 + 32768 + bBase + j * 2048 +
                      (xo0 ^ (kk * 64)));
  };

  // ---- prologue: tile0 fully + tile1's B-halves and A-half0 ----
  stageB(0, 0, 0); stageB(0, 1, 0); stageB(0, 2, 0); stageB(0, 3, 0);
  stageA(0, 0, 0); stageA(0, 1, 0); stageA(0, 2, 0); stageA(0, 3, 0);
  if (NT > 1) {
    stageB(1, 0, 64); stageB(1, 1, 64); stageB(1, 2, 64); stageB(1, 3, 64);
    stageA(1, 0, 64); stageA(1, 1, 64);
    asm volatile("s_waitcnt vmcnt(6)" ::: "memory");
  } else {
    asm volatile("s_waitcnt vmcnt(0)" ::: "memory");
  }
  BAR();

  for (int t = 0; t < NT; ++t) {
    int b = t & 1;
    int nb = b ^ 1;
    int kc1 = (t + 1) << 6;
    int kc2 = (t + 2) << 6;
    bool s1 = (t + 1 < NT);
    bool s2 = (t + 2 < NT);

#pragma unroll
    for (int q = 0; q < 4; ++q) {
      bf16x8 a00 = ldA(b, q, 0, 0);
      bf16x8 a01 = ldA(b, q, 0, 1);
      bf16x8 a10 = ldA(b, q, 1, 0);
      bf16x8 a11 = ldA(b, q, 1, 1);
      if (q == 0) {
#pragma unroll
        for (int j = 0; j < 4; ++j) {
          bf[j][0] = ldB(b, j, 0);
          bf[j][1] = ldB(b, j, 1);
        }
        if (s1) { stageA(nb, 2, kc1); stageA(nb, 3, kc1); }
      } else if (q == 1) {
        if (s2) { stageB(b, 0, kc2); stageB(b, 1, kc2); }
      } else if (q == 2) {
        if (s2) { stageB(b, 2, kc2); stageB(b, 3, kc2); }
      } else {
        if (s2) { stageA(b, 0, kc2); stageA(b, 1, kc2); }
      }
      BAR();
      asm volatile("s_waitcnt lgkmcnt(0)" ::: "memory");
      __builtin_amdgcn_sched_barrier(0);
      __builtin_amdgcn_s_setprio(1);
#pragma unroll
      for (int j = 0; j < 4; ++j) {
        acc[2 * q][j] = __builtin_amdgcn_mfma_f32_16x16x32_bf16(
            bf[j][0], a00, acc[2 * q][j], 0, 0, 0);
        acc[2 * q][j] = __builtin_amdgcn_mfma_f32_16x16x32_bf16(
            bf[j][1], a01, acc[2 * q][j], 0, 0, 0);
        acc[2 * q + 1][j] = __builtin_amdgcn_mfma_f32_16x16x32_bf16(
            bf[j][0], a10, acc[2 * q + 1][j], 0, 0, 0);
        acc[2 * q + 1][j] = __builtin_amdgcn_mfma_f32_16x16x32_bf16(
            bf[j][1], a11, acc[2 * q + 1][j], 0, 0, 0);
      }
      __builtin_amdgcn_s_setprio(0);
      if (q == 3 && s1) {
        if (s2) asm volatile("s_waitcnt vmcnt(6)" ::: "memory");
        else    asm volatile("s_waitcnt vmcnt(0)" ::: "memory");
      }
      BAR();
    }
  }

  // epilogue: m = m0+wm*128+i*16+col, n = n0+wn*64+j*16+quad*4+[0..3]
  // i-outer / j-inner: the 4 stores covering a row's 128B line are
  // back-to-back, so L2 merges the line before eviction (R1 had 2x
  // write amplification from j-outer partial-dirty evictions).
  float4 b4[4];
#pragma unroll
  for (int j = 0; j < 4; ++j)
    b4[j] = *reinterpret_cast<const float4*>(
        &bias[n0 + wn * 64 + j * 16 + quad * 4]);
#pragma unroll
  for (int i = 0; i < 8; ++i) {
    int m = m0 + wm * 128 + i * 16 + col;
#pragma unroll
    for (int j = 0; j < 4; ++j) {
      int nn = n0 + wn * 64 + j * 16 + quad * 4;
      u16x4 o;
      o.x = f2bf(elu1(acc[i][j][0] + b4[j].x));
      o.y = f2bf(elu1(acc[i][j][1] + b4[j].y));
      o.z = f2bf(elu1(acc[i][j][2] + b4[j].z));
      o.w = f2bf(elu1(acc[i][j][3] + b4[j].w));
      *reinterpret_cast<u16x4*>(&C[(long)m * N + nn]) = o;
    }
  }
}

// ---------------- fused L4: gate + softmax + expert heads + combine -------
__global__ __launch_bounds__(256) void final_combine_kernel(
    const u16* __restrict__ h3, const u16* __restrict__ W4t,
    const u16* __restrict__ gW4t, const float* __restrict__ eb4,
    const float* __restrict__ gb4, float* __restrict__ out) {
  const int H3 = 256;
  int tid = threadIdx.x;
  int lane = tid & 63;
  int w = tid >> 6;  // wave 0..3
  int col = lane & 15;
  int quad = lane >> 4;
  int r0 = blockIdx.x * 16;

  // ---- gate logits (every wave, same 16 rows) ----
  floatx4 g0 = {}, g1 = {};
  const u16* h3g = h3 + (long)E_EXP * B_SZ * H3;
#pragma unroll
  for (int k0 = 0; k0 < 256; k0 += 32) {
    bf16x8 a = ld_bf8(&h3g[(long)(r0 + col) * H3 + k0 + quad * 8]);
    bf16x8 b0 = ld_bf8(&gW4t[(long)col * H3 + k0 + quad * 8]);
    bf16x8 b1 = ld_bf8(&gW4t[(long)(16 + col) * H3 + k0 + quad * 8]);
    g0 = __builtin_amdgcn_mfma_f32_16x16x32_bf16(a, b0, g0, 0, 0, 0);
    g1 = __builtin_amdgcn_mfma_f32_16x16x32_bf16(a, b1, g1, 0, 0, 0);
  }

  // ---- softmax over 20 logits per row ----
  float w0[4], w1[4];
  float gbc0 = gb4[col];
  float gbc1 = (col < 4) ? gb4[16 + col] : 0.f;
#pragma unroll
  for (int r = 0; r < 4; ++r) {
    float v0 = g0[r] + gbc0;
    float v1 = (col < 4) ? (g1[r] + gbc1) : -1e30f;
    float m = fmaxf(v0, v1);
#pragma unroll
    for (int s = 1; s < 16; s <<= 1) m = fmaxf(m, __shfl_xor(m, s, 64));
    float e0 = __expf(v0 - m);
    float e1 = (col < 4) ? __expf(v1 - m) : 0.f;
    float ssum = e0 + e1;
#pragma unroll
    for (int s = 1; s < 16; s <<= 1) ssum += __shfl_xor(ssum, s, 64);
    w0[r] = e0 / ssum;
    w1[r] = e1 / ssum;
  }

  // ---- this wave's experts: w, w+4, w+8, w+12, w+16 ----
  floatx4 o0 = {}, o1 = {};
  for (int e = w; e < E_EXP; e += 4) {
    floatx4 a0 = {}, a1 = {};
    const u16* he = h3 + (long)e * B_SZ * H3;
    const u16* we = W4t + (long)e * 32 * H3;
#pragma unroll
    for (int k0 = 0; k0 < 256; k0 += 32) {
      bf16x8 a = ld_bf8(&he[(long)(r0 + col) * H3 + k0 + quad * 8]);
      bf16x8 b0 = ld_bf8(&we[(long)col * H3 + k0 + quad * 8]);
      bf16x8 b1 = ld_bf8(&we[(long)(16 + col) * H3 + k0 + quad * 8]);
      a0 = __builtin_amdgcn_mfma_f32_16x16x32_bf16(a, b0, a0, 0, 0, 0);
      a1 = __builtin_amdgcn_mfma_f32_16x16x32_bf16(a, b1, a1, 0, 0, 0);
    }
    float be0 = eb4[e * 32 + col];
    float be1 = eb4[e * 32 + 16 + col];
    int src = (lane & 48) + (e & 15);
#pragma unroll
    for (int r = 0; r < 4; ++r) {
      float wr = __shfl((e < 16) ? w0[r] : w1[r], src, 64);
      o0[r] += wr * (a0[r] + be0);
      o1[r] += wr * (a1[r] + be1);
    }
  }

  // ---- cross-wave reduce in LDS ----
  __shared__ float red[3][64][8];
  if (w > 0) {
#pragma unroll
    for (int r = 0; r < 4; ++r) {
      red[w - 1][lane][r] = o0[r];
      red[w - 1][lane][4 + r] = o1[r];
    }
  }
  __syncthreads();
  if (w == 0) {
#pragma unroll
    for (int ww = 0; ww < 3; ++ww)
#pragma unroll
      for (int r = 0; r < 4; ++r) {
        o0[r] += red[ww][lane][r];
        o1[r] += red[ww][lane][4 + r];
      }
#pragma unroll
    for (int r = 0; r < 4; ++r) {
      int row = r0 + quad * 4 + r;
      out[(long)row * 32 + col] = o0[r];
      out[(long)row * 32 + 16 + col] = o1[r];
    }
  }
}

// ---------------- host launch ----------------

static inline size_t align256(size_t x) { return (x + 255) & ~(size_t)255; }

extern "C" void kernel_launch(void* const* d_in, const int* in_sizes, int n_in,
                              void* d_out, int out_size, void* d_ws,
                              size_t ws_size, hipStream_t stream) {
  const float* obs = (const float*)d_in[0];
  const float* eW1 = (const float*)d_in[1];
  const float* eb1 = (const float*)d_in[2];
  const float* eW2 = (const float*)d_in[3];
  const float* eb2 = (const float*)d_in[4];
  const float* eW3 = (const float*)d_in[5];
  const float* eb3 = (const float*)d_in[6];
  const float* eW4 = (const float*)d_in[7];
  const float* eb4 = (const float*)d_in[8];
  const float* gW1 = (const float*)d_in[9];
  const float* gb1 = (const float*)d_in[10];
  const float* gW2 = (const float*)d_in[11];
  const float* gb2 = (const float*)d_in[12];
  const float* gW3 = (const float*)d_in[13];
  const float* gb3 = (const float*)d_in[14];
  const float* gW4 = (const float*)d_in[15];
  const float* gb4 = (const float*)d_in[16];
  float* out = (float*)d_out;
  char* ws = (char*)d_ws;

  // fixed workspace region
  size_t off = 0;
  size_t OFF_OBS = off;  off = align256(off + (size_t)B_SZ * 512 * 2);
  size_t OFF_W1T = off;  off = align256(off + (size_t)NE * 1024 * 512 * 2);
  size_t OFF_W2T = off;  off = align256(off + (size_t)NE * 512 * 1024 * 2);
  size_t OFF_W3T = off;  off = align256(off + (size_t)NE * 256 * 512 * 2);
  size_t OFF_W4T = off;  off = align256(off + (size_t)E_EXP * 32 * 256 * 2);
  size_t OFF_GW4T = off; off = align256(off + (size_t)32 * 256 * 2);
  size_t OFF_B1 = off;   off = align256(off + (size_t)NE * 1024 * 4);
  size_t OFF_B2 = off;   off = align256(off + (size_t)NE * 512 * 4);
  size_t OFF_B3 = off;   off = align256(off + (size_t)NE * 256 * 4);
  size_t OFF_H3 = off;   off = align256(off + (size_t)NE * B_SZ * 256 * 2);

  // adaptive batch-chunked h1/h2: every dispatch covers all 21 experts
  int chunk = B_SZ;
  size_t OFF_H1 = off;
  while (chunk > 512) {
    size_t need = (size_t)NE * chunk * 1024 * 2 + (size_t)NE * chunk * 512 * 2;
    if (OFF_H1 + need <= ws_size) break;
    chunk >>= 1;
  }
  size_t OFF_H2 = align256(OFF_H1 + (size_t)NE * chunk * 1024 * 2);

  u16* obs_bf = (u16*)(ws + OFF_OBS);
  u16* W1t = (u16*)(ws + OFF_W1T);
  u16* W2t = (u16*)(ws + OFF_W2T);
  u16* W3t = (u16*)(ws + OFF_W3T);
  u16* W4t = (u16*)(ws + OFF_W4T);
  u16* gW4t = (u16*)(ws + OFF_GW4T);
  float* b1 = (float*)(ws + OFF_B1);
  float* b2 = (float*)(ws + OFF_B2);
  float* b3 = (float*)(ws + OFF_B3);
  u16* h3 = (u16*)(ws + OFF_H3);
  u16* h1 = (u16*)(ws + OFF_H1);
  u16* h2 = (u16*)(ws + OFF_H2);

  // --- prep: obs convert + bias concat (1), all transposes (1) ---
  prep_small_kernel<<<2048 + (NE * 1792 + 255) / 256, 256, 0, stream>>>(
      obs, obs_bf, eb1, gb1, eb2, gb2, eb3, gb3, b1, b2, b3);
  transpose_all_kernel<<<TRANS_BLOCKS, 256, 0, stream>>>(
      eW1, gW1, eW2, gW2, eW3, gW3, eW4, gW4, W1t, W2t, W3t, W4t, gW4t);

  int ntm = chunk / BM;  // BM = 256
  // --- trunk layers 1..3, batch-chunked, 8-phase 256x256 grouped GEMM ---
  for (int bc = 0; bc < B_SZ; bc += chunk) {
    gemm_bias_elu_kernel<<<NE * 4 * ntm, 512, 0, stream>>>(
        obs_bf + (size_t)bc * 512, 0L,
        W1t, (long)1024 * 512,
        b1, 1024L,
        h1, (long)chunk * 1024, chunk, 1024, 512, 4, ntm);
    gemm_bias_elu_kernel<<<NE * 2 * ntm, 512, 0, stream>>>(
        h1, (long)chunk * 1024,
        W2t, (long)512 * 1024,
        b2, 512L,
        h2, (long)chunk * 512, chunk, 512, 1024, 2, ntm);
    gemm_bias_elu_kernel<<<NE * 1 * ntm, 512, 0, stream>>>(
        h2, (long)chunk * 512,
        W3t, (long)256 * 512,
        b3, 256L,
        h3 + (size_t)bc * 256, (long)B_SZ * 256, chunk, 256, 512, 1, ntm);
  }

  // --- fused layer-4 + softmax + combine ---
  final_combine_kernel<<<B_SZ / 16, 256, 0, stream>>>(h3, W4t, gW4t, eb4, gb4,
                                                      out);
}

// Round 4
// 505.748 us; speedup vs baseline: 1.0438x; 1.0177x over previous
//
#include <hip/hip_runtime.h>

#define B_SZ 4096
#define E_EXP 20
#define NE 21  // 20 experts + gate share the trunk

typedef unsigned short u16;
typedef __bf16 bf16x8 __attribute__((ext_vector_type(8)));
typedef u16 u16x8 __attribute__((ext_vector_type(8)));
typedef u16 u16x4 __attribute__((ext_vector_type(4)));
typedef float floatx4 __attribute__((ext_vector_type(4)));

static __device__ __forceinline__ u16 f2bf(float f) {
  unsigned u = __builtin_bit_cast(unsigned, f);
  u += 0x7fffu + ((u >> 16) & 1u);  // RNE
  return (u16)(u >> 16);
}

static __device__ __forceinline__ float elu1(float v) {
  return v > 0.f ? v : (__expf(v) - 1.f);
}

static __device__ __forceinline__ bf16x8 ld_bf8(const u16* p) {
  u16x8 v = *reinterpret_cast<const u16x8*>(p);
  return __builtin_bit_cast(bf16x8, v);
}

// async global->LDS DMA, 16B per lane. LDS dest is wave-uniform base +
// lane*16 — lds ptr must be linear in thread order (no padding!).
static __device__ __forceinline__ void gld_lds16(const u16* g, u16* l) {
  __builtin_amdgcn_global_load_lds(
      (const __attribute__((address_space(1))) unsigned int*)g,
      (__attribute__((address_space(3))) unsigned int*)l, 16, 0, 0);
}

// ---------------- prep: obs convert + bias concat, one dispatch ----------

__global__ void prep_small_kernel(
    const float* __restrict__ obs, u16* __restrict__ obs_bf,
    const float* __restrict__ eb1, const float* __restrict__ gb1,
    const float* __restrict__ eb2, const float* __restrict__ gb2,
    const float* __restrict__ eb3, const float* __restrict__ gb3,
    float* __restrict__ b1, float* __restrict__ b2, float* __restrict__ b3) {
  int bid = blockIdx.x;
  if (bid < 2048) {  // obs: B_SZ*512 floats, 4/thread
    int i = (bid * 256 + threadIdx.x) * 4;
    float4 v = *reinterpret_cast<const float4*>(obs + i);
    u16x4 o;
    o.x = f2bf(v.x); o.y = f2bf(v.y); o.z = f2bf(v.z); o.w = f2bf(v.w);
    *reinterpret_cast<u16x4*>(obs_bf + i) = o;
  } else {
    int i = (bid - 2048) * 256 + threadIdx.x;
    const int S1 = NE * 1024, S2 = NE * 512, S3 = NE * 256;
    if (i < S1) {
      b1[i] = (i < E_EXP * 1024) ? eb1[i] : gb1[i - E_EXP * 1024];
    } else if (i < S1 + S2) {
      int j = i - S1;
      b2[j] = (j < E_EXP * 512) ? eb2[j] : gb2[j - E_EXP * 512];
    } else if (i < S1 + S2 + S3) {
      int j = i - S1 - S2;
      b3[j] = (j < E_EXP * 256) ? eb3[j] : gb3[j - E_EXP * 256];
    }
  }
}

// ---------------- all weight transposes, one job-table dispatch ----------
#define TRANS_BLOCKS 6132

__global__ __launch_bounds__(256) void transpose_all_kernel(
    const float* __restrict__ eW1, const float* __restrict__ gW1,
    const float* __restrict__ eW2, const float* __restrict__ gW2,
    const float* __restrict__ eW3, const float* __restrict__ gW3,
    const float* __restrict__ eW4, const float* __restrict__ gW4,
    u16* __restrict__ W1t, u16* __restrict__ W2t, u16* __restrict__ W3t,
    u16* __restrict__ W4t, u16* __restrict__ gW4t) {
  int f = blockIdx.x;
  const float *srcE, *srcG;
  u16* dstBase;
  int rem, K, N, Nout, kxt, tpm, nm;
  if (f < 2688) {
    rem = f;        srcE = eW1; srcG = gW1; dstBase = W1t;
    K = 512;  N = 1024; Nout = 1024; kxt = 8;  tpm = 128; nm = 20;
  } else if (f < 5376) {
    rem = f - 2688; srcE = eW2; srcG = gW2; dstBase = W2t;
    K = 1024; N = 512;  Nout = 512;  kxt = 16; tpm = 128; nm = 20;
  } else if (f < 6048) {
    rem = f - 5376; srcE = eW3; srcG = gW3; dstBase = W3t;
    K = 512;  N = 256;  Nout = 256;  kxt = 8;  tpm = 32;  nm = 20;
  } else if (f < 6128) {
    rem = f - 6048; srcE = eW4; srcG = nullptr; dstBase = W4t;
    K = 256;  N = 32;   Nout = 32;   kxt = 4;  tpm = 4;   nm = 99;
  } else {
    rem = f - 6128; srcE = gW4; srcG = nullptr; dstBase = gW4t;
    K = 256;  N = 20;   Nout = 32;   kxt = 4;  tpm = 4;   nm = 99;
  }
  int mat = rem / tpm;
  int t = rem % tpm;
  const float* src = (mat < nm) ? (srcE + (long)mat * K * N) : srcG;
  u16* dst = dstBase + (long)mat * Nout * K;
  int kbase = (t % kxt) * 64;
  int nbase = (t / kxt) * 64;

  __shared__ float tl[64][65];
  int tid = threadIdx.x;
  int kk = tid >> 4;        // 0..15
  int n4 = (tid & 15) * 4;  // 0..60
#pragma unroll
  for (int p = 0; p < 4; ++p) {
    int k = kbase + p * 16 + kk;  // always < K (grid exact)
    int n = nbase + n4;
    float4 v = make_float4(0.f, 0.f, 0.f, 0.f);
    if (n + 3 < N) {
      v = *reinterpret_cast<const float4*>(&src[(long)k * N + n]);
    } else {
      float* vp = &v.x;
      for (int j = 0; j < 4; ++j)
        if (n + j < N) vp[j] = src[(long)k * N + n + j];
    }
    tl[p * 16 + kk][n4 + 0] = v.x;
    tl[p * 16 + kk][n4 + 1] = v.y;
    tl[p * 16 + kk][n4 + 2] = v.z;
    tl[p * 16 + kk][n4 + 3] = v.w;
  }
  __syncthreads();

  int kk8 = (tid & 7) * 8;
#pragma unroll
  for (int p = 0; p < 2; ++p) {
    int ln = p * 32 + (tid >> 3);  // 0..63
    int n = nbase + ln;
    if (n < Nout) {
      u16x8 o;
#pragma unroll
      for (int j = 0; j < 8; ++j) o[j] = f2bf(tl[kk8 + j][ln]);
      *reinterpret_cast<u16x8*>(&dst[(long)n * K + kbase + kk8]) = o;
    }
  }
}

// ---------------- grouped GEMM + bias + ELU ----------------
// C[M,N] = elu(A[M,K] @ Wt[N,K]^T + bias), bf16 in/out, fp32 accumulate.
// R5 structure (128x128, BK=64 dual-panel, global_load_lds, normal stores)
// + XCD-CLUSTERED 1-D work decode (contiguous expert-major range per XCD)
// + T2 LDS swizzle (this round): R0 measured SQ_LDS_BANK_CONFLICT=5.5M per
//   dispatch — 64B-row LDS tiles read as b128 give an 8-way bank conflict
//   (bank = (row&1)*16 + quad*4). Fix via the m173 double-XOR pattern:
//   staging thread loads global k-chunk (tid&3)^((tid>>2)&3) so LDS linear
//   dest holds row-permuted chunks; fragment reads use chunk quad^(col&3);
//   row&3 == col&3 makes the XORs cancel -> lane retrieves its original
//   k-chunk (numerically identical), but the wave's 64 slots now tile all
//   32 banks evenly. Verified mechanism: R1-R3 ports showed conflicts -> 0.

#define BM 128
#define BN 128

__global__ __launch_bounds__(256) void gemm_bias_elu_kernel(
    const u16* __restrict__ A_base, long a_estride,
    const u16* __restrict__ Wt_base, long w_estride,
    const float* __restrict__ bias_base, long b_estride,
    u16* __restrict__ C_base, long c_estride,
    int M, int N, int K, int ntn, int ntm) {
  // XCD-clustered decode (gridDim.x divisible by 8)
  int per = gridDim.x >> 3;
  int wid = (blockIdx.x & 7) * per + (blockIdx.x >> 3);
  int tpe = ntn * ntm;
  int e = wid / tpe;
  int rem = wid - e * tpe;
  int mt = rem / ntn;        // m-tile (outer within expert)
  int nt = rem - mt * ntn;   // n-tile (inner -> A-tile reuse in time)
  int m0 = mt * BM;
  int n0 = nt * BN;

  const u16* A = A_base + (long)e * a_estride;
  const u16* Wt = Wt_base + (long)e * w_estride;
  const float* bias = bias_base + (long)e * b_estride;
  u16* C = C_base + (long)e * c_estride;

  // [panel][row][32] — lane-linear for global_load_lds (no padding)
  __shared__ u16 As[2 * BM * 32];
  __shared__ u16 Bs[2 * BN * 32];

  int tid = threadIdx.x;
  int lane = tid & 63;
  int w = tid >> 6;            // wave 0..3 in 2x2
  int wm = (w >> 1) * 64;
  int wn = (w & 1) * 64;
  int col = lane & 15;
  int quad = lane >> 4;

  floatx4 acc[4][4] = {};

  int srow = tid >> 2;         // 0..63
  // T2: pre-swizzled global source chunk (XOR with staged row's low bits)
  int scol = ((tid & 3) ^ ((tid >> 2) & 3)) * 8;  // 16B chunk within 64B
  const u16* gA = &A[(long)(m0 + srow) * K + scol];
  const u16* gB = &Wt[(long)(n0 + srow) * K + scol];
  long rowK = (long)64 * K;

  // T2: swizzled fragment-read chunk; row&3 == col&3 cancels staging XOR
  int xoq = (quad ^ (col & 3)) * 8;

  for (int k0 = 0; k0 < K; k0 += 64) {
    __syncthreads();  // prior LDS reads done before overwrite
    gld_lds16(gA + k0, &As[(size_t)tid * 8]);
    gld_lds16(gA + rowK + k0, &As[(size_t)(256 + tid) * 8]);
    gld_lds16(gA + k0 + 32, &As[(size_t)(512 + tid) * 8]);
    gld_lds16(gA + rowK + k0 + 32, &As[(size_t)(768 + tid) * 8]);
    gld_lds16(gB + k0, &Bs[(size_t)tid * 8]);
    gld_lds16(gB + rowK + k0, &Bs[(size_t)(256 + tid) * 8]);
    gld_lds16(gB + k0 + 32, &Bs[(size_t)(512 + tid) * 8]);
    gld_lds16(gB + rowK + k0 + 32, &Bs[(size_t)(768 + tid) * 8]);
    __syncthreads();  // drains vmcnt -> staged data visible

#pragma unroll
    for (int kk = 0; kk < 2; ++kk) {
      bf16x8 xf[4], wf[4];
#pragma unroll
      for (int t = 0; t < 4; ++t) {
        xf[t] = __builtin_bit_cast(bf16x8,
            *reinterpret_cast<u16x8*>(
                &As[kk * BM * 32 + (wm + t * 16 + col) * 32 + xoq]));
        wf[t] = __builtin_bit_cast(bf16x8,
            *reinterpret_cast<u16x8*>(
                &Bs[kk * BN * 32 + (wn + t * 16 + col) * 32 + xoq]));
      }
#pragma unroll
      for (int i = 0; i < 4; ++i)
#pragma unroll
        for (int j = 0; j < 4; ++j)
          acc[i][j] = __builtin_amdgcn_mfma_f32_16x16x32_bf16(
              wf[j], xf[i], acc[i][j], 0, 0, 0);
    }
  }

  // epilogue: lane holds m = m0+wm+i*16+col, n = n0+wn+j*16+quad*4+[0..3]
#pragma unroll
  for (int j = 0; j < 4; ++j) {
    int nn = n0 + wn + j * 16 + quad * 4;
    float4 b4 = *reinterpret_cast<const float4*>(&bias[nn]);
#pragma unroll
    for (int i = 0; i < 4; ++i) {
      int m = m0 + wm + i * 16 + col;
      u16x4 o;
      o.x = f2bf(elu1(acc[i][j][0] + b4.x));
      o.y = f2bf(elu1(acc[i][j][1] + b4.y));
      o.z = f2bf(elu1(acc[i][j][2] + b4.z));
      o.w = f2bf(elu1(acc[i][j][3] + b4.w));
      *reinterpret_cast<u16x4*>(&C[(long)m * N + nn]) = o;
    }
  }
}

// ---------------- fused L4: gate + softmax + expert heads + combine -------
__global__ __launch_bounds__(256) void final_combine_kernel(
    const u16* __restrict__ h3, const u16* __restrict__ W4t,
    const u16* __restrict__ gW4t, const float* __restrict__ eb4,
    const float* __restrict__ gb4, float* __restrict__ out) {
  const int H3 = 256;
  int tid = threadIdx.x;
  int lane = tid & 63;
  int w = tid >> 6;  // wave 0..3
  int col = lane & 15;
  int quad = lane >> 4;
  int r0 = blockIdx.x * 16;

  // ---- gate logits (every wave, same 16 rows) ----
  floatx4 g0 = {}, g1 = {};
  const u16* h3g = h3 + (long)E_EXP * B_SZ * H3;
#pragma unroll
  for (int k0 = 0; k0 < 256; k0 += 32) {
    bf16x8 a = ld_bf8(&h3g[(long)(r0 + col) * H3 + k0 + quad * 8]);
    bf16x8 b0 = ld_bf8(&gW4t[(long)col * H3 + k0 + quad * 8]);
    bf16x8 b1 = ld_bf8(&gW4t[(long)(16 + col) * H3 + k0 + quad * 8]);
    g0 = __builtin_amdgcn_mfma_f32_16x16x32_bf16(a, b0, g0, 0, 0, 0);
    g1 = __builtin_amdgcn_mfma_f32_16x16x32_bf16(a, b1, g1, 0, 0, 0);
  }

  // ---- softmax over 20 logits per row ----
  float w0[4], w1[4];
  float gbc0 = gb4[col];
  float gbc1 = (col < 4) ? gb4[16 + col] : 0.f;
#pragma unroll
  for (int r = 0; r < 4; ++r) {
    float v0 = g0[r] + gbc0;
    float v1 = (col < 4) ? (g1[r] + gbc1) : -1e30f;
    float m = fmaxf(v0, v1);
#pragma unroll
    for (int s = 1; s < 16; s <<= 1) m = fmaxf(m, __shfl_xor(m, s, 64));
    float e0 = __expf(v0 - m);
    float e1 = (col < 4) ? __expf(v1 - m) : 0.f;
    float ssum = e0 + e1;
#pragma unroll
    for (int s = 1; s < 16; s <<= 1) ssum += __shfl_xor(ssum, s, 64);
    w0[r] = e0 / ssum;
    w1[r] = e1 / ssum;
  }

  // ---- this wave's experts: w, w+4, w+8, w+12, w+16 ----
  floatx4 o0 = {}, o1 = {};
  for (int e = w; e < E_EXP; e += 4) {
    floatx4 a0 = {}, a1 = {};
    const u16* he = h3 + (long)e * B_SZ * H3;
    const u16* we = W4t + (long)e * 32 * H3;
#pragma unroll
    for (int k0 = 0; k0 < 256; k0 += 32) {
      bf16x8 a = ld_bf8(&he[(long)(r0 + col) * H3 + k0 + quad * 8]);
      bf16x8 b0 = ld_bf8(&we[(long)col * H3 + k0 + quad * 8]);
      bf16x8 b1 = ld_bf8(&we[(long)(16 + col) * H3 + k0 + quad * 8]);
      a0 = __builtin_amdgcn_mfma_f32_16x16x32_bf16(a, b0, a0, 0, 0, 0);
      a1 = __builtin_amdgcn_mfma_f32_16x16x32_bf16(a, b1, a1, 0, 0, 0);
    }
    float be0 = eb4[e * 32 + col];
    float be1 = eb4[e * 32 + 16 + col];
    int src = (lane & 48) + (e & 15);
#pragma unroll
    for (int r = 0; r < 4; ++r) {
      float wr = __shfl((e < 16) ? w0[r] : w1[r], src, 64);
      o0[r] += wr * (a0[r] + be0);
      o1[r] += wr * (a1[r] + be1);
    }
  }

  // ---- cross-wave reduce in LDS ----
  __shared__ float red[3][64][8];
  if (w > 0) {
#pragma unroll
    for (int r = 0; r < 4; ++r) {
      red[w - 1][lane][r] = o0[r];
      red[w - 1][lane][4 + r] = o1[r];
    }
  }
  __syncthreads();
  if (w == 0) {
#pragma unroll
    for (int ww = 0; ww < 3; ++ww)
#pragma unroll
      for (int r = 0; r < 4; ++r) {
        o0[r] += red[ww][lane][r];
        o1[r] += red[ww][lane][4 + r];
      }
#pragma unroll
    for (int r = 0; r < 4; ++r) {
      int row = r0 + quad * 4 + r;
      out[(long)row * 32 + col] = o0[r];
      out[(long)row * 32 + 16 + col] = o1[r];
    }
  }
}

// ---------------- host launch ----------------

static inline size_t align256(size_t x) { return (x + 255) & ~(size_t)255; }

extern "C" void kernel_launch(void* const* d_in, const int* in_sizes, int n_in,
                              void* d_out, int out_size, void* d_ws,
                              size_t ws_size, hipStream_t stream) {
  const float* obs = (const float*)d_in[0];
  const float* eW1 = (const float*)d_in[1];
  const float* eb1 = (const float*)d_in[2];
  const float* eW2 = (const float*)d_in[3];
  const float* eb2 = (const float*)d_in[4];
  const float* eW3 = (const float*)d_in[5];
  const float* eb3 = (const float*)d_in[6];
  const float* eW4 = (const float*)d_in[7];
  const float* eb4 = (const float*)d_in[8];
  const float* gW1 = (const float*)d_in[9];
  const float* gb1 = (const float*)d_in[10];
  const float* gW2 = (const float*)d_in[11];
  const float* gb2 = (const float*)d_in[12];
  const float* gW3 = (const float*)d_in[13];
  const float* gb3 = (const float*)d_in[14];
  const float* gW4 = (const float*)d_in[15];
  const float* gb4 = (const float*)d_in[16];
  float* out = (float*)d_out;
  char* ws = (char*)d_ws;

  // fixed workspace region
  size_t off = 0;
  size_t OFF_OBS = off;  off = align256(off + (size_t)B_SZ * 512 * 2);
  size_t OFF_W1T = off;  off = align256(off + (size_t)NE * 1024 * 512 * 2);
  size_t OFF_W2T = off;  off = align256(off + (size_t)NE * 512 * 1024 * 2);
  size_t OFF_W3T = off;  off = align256(off + (size_t)NE * 256 * 512 * 2);
  size_t OFF_W4T = off;  off = align256(off + (size_t)E_EXP * 32 * 256 * 2);
  size_t OFF_GW4T = off; off = align256(off + (size_t)32 * 256 * 2);
  size_t OFF_B1 = off;   off = align256(off + (size_t)NE * 1024 * 4);
  size_t OFF_B2 = off;   off = align256(off + (size_t)NE * 512 * 4);
  size_t OFF_B3 = off;   off = align256(off + (size_t)NE * 256 * 4);
  size_t OFF_H3 = off;   off = align256(off + (size_t)NE * B_SZ * 256 * 2);

  // adaptive batch-chunked h1/h2: every dispatch covers all 21 experts
  int chunk = B_SZ;
  size_t OFF_H1 = off;
  while (chunk > 512) {
    size_t need = (size_t)NE * chunk * 1024 * 2 + (size_t)NE * chunk * 512 * 2;
    if (OFF_H1 + need <= ws_size) break;
    chunk >>= 1;
  }
  size_t OFF_H2 = align256(OFF_H1 + (size_t)NE * chunk * 1024 * 2);

  u16* obs_bf = (u16*)(ws + OFF_OBS);
  u16* W1t = (u16*)(ws + OFF_W1T);
  u16* W2t = (u16*)(ws + OFF_W2T);
  u16* W3t = (u16*)(ws + OFF_W3T);
  u16* W4t = (u16*)(ws + OFF_W4T);
  u16* gW4t = (u16*)(ws + OFF_GW4T);
  float* b1 = (float*)(ws + OFF_B1);
  float* b2 = (float*)(ws + OFF_B2);
  float* b3 = (float*)(ws + OFF_B3);
  u16* h3 = (u16*)(ws + OFF_H3);
  u16* h1 = (u16*)(ws + OFF_H1);
  u16* h2 = (u16*)(ws + OFF_H2);

  // --- prep: obs convert + bias concat (1), all transposes (1) ---
  prep_small_kernel<<<2048 + (NE * 1792 + 255) / 256, 256, 0, stream>>>(
      obs, obs_bf, eb1, gb1, eb2, gb2, eb3, gb3, b1, b2, b3);
  transpose_all_kernel<<<TRANS_BLOCKS, 256, 0, stream>>>(
      eW1, gW1, eW2, gW2, eW3, gW3, eW4, gW4, W1t, W2t, W3t, W4t, gW4t);

  int ntm = chunk / BM;
  // --- trunk layers 1..3, batch-chunked, XCD-clustered 1-D grids ---
  for (int bc = 0; bc < B_SZ; bc += chunk) {
    gemm_bias_elu_kernel<<<NE * 8 * ntm, 256, 0, stream>>>(
        obs_bf + (size_t)bc * 512, 0L,
        W1t, (long)1024 * 512,
        b1, 1024L,
        h1, (long)chunk * 1024, chunk, 1024, 512, 8, ntm);
    gemm_bias_elu_kernel<<<NE * 4 * ntm, 256, 0, stream>>>(
        h1, (long)chunk * 1024,
        W2t, (long)512 * 1024,
        b2, 512L,
        h2, (long)chunk * 512, chunk, 512, 1024, 4, ntm);
    gemm_bias_elu_kernel<<<NE * 2 * ntm, 256, 0, stream>>>(
        h2, (long)chunk * 512,
        W3t, (long)256 * 512,
        b3, 256L,
        h3 + (size_t)bc * 256, (long)B_SZ * 256, chunk, 256, 512, 2, ntm);
  }

  // --- fused layer-4 + softmax + combine ---
  final_combine_kernel<<<B_SZ / 16, 256, 0, stream>>>(h3, W4t, gW4t, eb4, gb4,
                                                      out);
}

// Round 5
// 504.146 us; speedup vs baseline: 1.0471x; 1.0032x over previous
//
#include <hip/hip_runtime.h>

#define B_SZ 4096
#define E_EXP 20
#define NE 21  // 20 experts + gate share the trunk

typedef unsigned short u16;
typedef __bf16 bf16x8 __attribute__((ext_vector_type(8)));
typedef u16 u16x8 __attribute__((ext_vector_type(8)));
typedef u16 u16x4 __attribute__((ext_vector_type(4)));
typedef float floatx4 __attribute__((ext_vector_type(4)));

static __device__ __forceinline__ u16 f2bf(float f) {
  unsigned u = __builtin_bit_cast(unsigned, f);
  u += 0x7fffu + ((u >> 16) & 1u);  // RNE
  return (u16)(u >> 16);
}

static __device__ __forceinline__ float elu1(float v) {
  return v > 0.f ? v : (__expf(v) - 1.f);
}

static __device__ __forceinline__ bf16x8 ld_bf8(const u16* p) {
  u16x8 v = *reinterpret_cast<const u16x8*>(p);
  return __builtin_bit_cast(bf16x8, v);
}

// async global->LDS DMA, 16B per lane. LDS dest is wave-uniform base +
// lane*16 — lds ptr must be linear in thread order (no padding!).
static __device__ __forceinline__ void gld_lds16(const u16* g, u16* l) {
  __builtin_amdgcn_global_load_lds(
      (const __attribute__((address_space(1))) unsigned int*)g,
      (__attribute__((address_space(3))) unsigned int*)l, 16, 0, 0);
}

// ---------------- prep: obs convert + bias concat, one dispatch ----------

__global__ void prep_small_kernel(
    const float* __restrict__ obs, u16* __restrict__ obs_bf,
    const float* __restrict__ eb1, const float* __restrict__ gb1,
    const float* __restrict__ eb2, const float* __restrict__ gb2,
    const float* __restrict__ eb3, const float* __restrict__ gb3,
    float* __restrict__ b1, float* __restrict__ b2, float* __restrict__ b3) {
  int bid = blockIdx.x;
  if (bid < 2048) {  // obs: B_SZ*512 floats, 4/thread
    int i = (bid * 256 + threadIdx.x) * 4;
    float4 v = *reinterpret_cast<const float4*>(obs + i);
    u16x4 o;
    o.x = f2bf(v.x); o.y = f2bf(v.y); o.z = f2bf(v.z); o.w = f2bf(v.w);
    *reinterpret_cast<u16x4*>(obs_bf + i) = o;
  } else {
    int i = (bid - 2048) * 256 + threadIdx.x;
    const int S1 = NE * 1024, S2 = NE * 512, S3 = NE * 256;
    if (i < S1) {
      b1[i] = (i < E_EXP * 1024) ? eb1[i] : gb1[i - E_EXP * 1024];
    } else if (i < S1 + S2) {
      int j = i - S1;
      b2[j] = (j < E_EXP * 512) ? eb2[j] : gb2[j - E_EXP * 512];
    } else if (i < S1 + S2 + S3) {
      int j = i - S1 - S2;
      b3[j] = (j < E_EXP * 256) ? eb3[j] : gb3[j - E_EXP * 256];
    }
  }
}

// ---------------- all weight transposes, one job-table dispatch ----------
#define TRANS_BLOCKS 6132

__global__ __launch_bounds__(256) void transpose_all_kernel(
    const float* __restrict__ eW1, const float* __restrict__ gW1,
    const float* __restrict__ eW2, const float* __restrict__ gW2,
    const float* __restrict__ eW3, const float* __restrict__ gW3,
    const float* __restrict__ eW4, const float* __restrict__ gW4,
    u16* __restrict__ W1t, u16* __restrict__ W2t, u16* __restrict__ W3t,
    u16* __restrict__ W4t, u16* __restrict__ gW4t) {
  int f = blockIdx.x;
  const float *srcE, *srcG;
  u16* dstBase;
  int rem, K, N, Nout, kxt, tpm, nm;
  if (f < 2688) {
    rem = f;        srcE = eW1; srcG = gW1; dstBase = W1t;
    K = 512;  N = 1024; Nout = 1024; kxt = 8;  tpm = 128; nm = 20;
  } else if (f < 5376) {
    rem = f - 2688; srcE = eW2; srcG = gW2; dstBase = W2t;
    K = 1024; N = 512;  Nout = 512;  kxt = 16; tpm = 128; nm = 20;
  } else if (f < 6048) {
    rem = f - 5376; srcE = eW3; srcG = gW3; dstBase = W3t;
    K = 512;  N = 256;  Nout = 256;  kxt = 8;  tpm = 32;  nm = 20;
  } else if (f < 6128) {
    rem = f - 6048; srcE = eW4; srcG = nullptr; dstBase = W4t;
    K = 256;  N = 32;   Nout = 32;   kxt = 4;  tpm = 4;   nm = 99;
  } else {
    rem = f - 6128; srcE = gW4; srcG = nullptr; dstBase = gW4t;
    K = 256;  N = 20;   Nout = 32;   kxt = 4;  tpm = 4;   nm = 99;
  }
  int mat = rem / tpm;
  int t = rem % tpm;
  const float* src = (mat < nm) ? (srcE + (long)mat * K * N) : srcG;
  u16* dst = dstBase + (long)mat * Nout * K;
  int kbase = (t % kxt) * 64;
  int nbase = (t / kxt) * 64;

  __shared__ float tl[64][65];
  int tid = threadIdx.x;
  int kk = tid >> 4;        // 0..15
  int n4 = (tid & 15) * 4;  // 0..60
#pragma unroll
  for (int p = 0; p < 4; ++p) {
    int k = kbase + p * 16 + kk;  // always < K (grid exact)
    int n = nbase + n4;
    float4 v = make_float4(0.f, 0.f, 0.f, 0.f);
    if (n + 3 < N) {
      v = *reinterpret_cast<const float4*>(&src[(long)k * N + n]);
    } else {
      float* vp = &v.x;
      for (int j = 0; j < 4; ++j)
        if (n + j < N) vp[j] = src[(long)k * N + n + j];
    }
    tl[p * 16 + kk][n4 + 0] = v.x;
    tl[p * 16 + kk][n4 + 1] = v.y;
    tl[p * 16 + kk][n4 + 2] = v.z;
    tl[p * 16 + kk][n4 + 3] = v.w;
  }
  __syncthreads();

  int kk8 = (tid & 7) * 8;
#pragma unroll
  for (int p = 0; p < 2; ++p) {
    int ln = p * 32 + (tid >> 3);  // 0..63
    int n = nbase + ln;
    if (n < Nout) {
      u16x8 o;
#pragma unroll
      for (int j = 0; j < 8; ++j) o[j] = f2bf(tl[kk8 + j][ln]);
      *reinterpret_cast<u16x8*>(&dst[(long)n * K + kbase + kk8]) = o;
    }
  }
}

// ---------------- grouped GEMM + bias + ELU ----------------
// C[M,N] = elu(A[M,K] @ Wt[N,K]^T + bias), bf16 in/out, fp32 accumulate.
// R5 structure (128x128, BK=64, global_load_lds, normal stores)
// + XCD-CLUSTERED 1-D work decode (contiguous expert-major range per XCD)
// + 128B-ROW LDS + 8-slot XOR swizzle (R4 post-mortem):
//   The old dual-panel layout had 64B rows -> byte%128 = (row&1)*64 +
//   slot*16 with only 4 slot values reachable; any within-group XOR leaves
//   8 lanes per 16B bank-group -> the measured invariant +4 cyc per
//   ds_read_b128 (5,505,024 = 2688 blocks x 512 reads x 4). The 256²
//   kernel (R1-R3) with 128B rows + slot = chunk^(col&7) measured ZERO
//   conflicts: per 8-lane service phase (col&7 spans 0..7) the XOR hits
//   all 8 16B slots of the 128B line. This round ports exactly that
//   layout: As/Bs = [row][BK=64] (128B rows); staging thread (row=tid>>3,
//   slot=tid&7) fetches global chunk (tid&7)^((tid>>3)&7) (pre-swizzled
//   SOURCE, linear LDS dest — rule #21); reads use slot
//   (kk*4+quad)^(col&7); row&7==col&7 cancels -> identical data.

#define BM 128
#define BN 128

__global__ __launch_bounds__(256) void gemm_bias_elu_kernel(
    const u16* __restrict__ A_base, long a_estride,
    const u16* __restrict__ Wt_base, long w_estride,
    const float* __restrict__ bias_base, long b_estride,
    u16* __restrict__ C_base, long c_estride,
    int M, int N, int K, int ntn, int ntm) {
  // XCD-clustered decode (gridDim.x divisible by 8)
  int per = gridDim.x >> 3;
  int wid = (blockIdx.x & 7) * per + (blockIdx.x >> 3);
  int tpe = ntn * ntm;
  int e = wid / tpe;
  int rem = wid - e * tpe;
  int mt = rem / ntn;        // m-tile (outer within expert)
  int nt = rem - mt * ntn;   // n-tile (inner -> A-tile reuse in time)
  int m0 = mt * BM;
  int n0 = nt * BN;

  const u16* A = A_base + (long)e * a_estride;
  const u16* Wt = Wt_base + (long)e * w_estride;
  const float* bias = bias_base + (long)e * b_estride;
  u16* C = C_base + (long)e * c_estride;

  // [row][64 k-elems] = 128B rows; 16KB each
  __shared__ u16 As[BM * 64];
  __shared__ u16 Bs[BN * 64];

  int tid = threadIdx.x;
  int lane = tid & 63;
  int w = tid >> 6;            // wave 0..3 in 2x2
  int wm = (w >> 1) * 64;
  int wn = (w & 1) * 64;
  int col = lane & 15;
  int quad = lane >> 4;

  floatx4 acc[4][4] = {};

  // staging: thread -> (row = tid>>3 within 32-row group, slot = tid&7),
  // global chunk pre-swizzled: (tid&7) ^ ((tid>>3)&7)
  int srow = tid >> 3;                             // 0..31
  int gchunk = (tid & 7) ^ (srow & 7);
  const u16* gA = &A[(long)(m0 + srow) * K + gchunk * 8];
  const u16* gB = &Wt[(long)(n0 + srow) * K + gchunk * 8];
  long rowK = (long)32 * K;                        // 32 rows per instruction

  // read: slot s(kk) = (kk*4 + quad) ^ (col&7); s1 = s0 ^ 4 (chunk units)
  int s0 = (quad ^ (col & 7)) * 8;                 // u16 offset of 16B slot
  int aRow = (wm + col) * 64;
  int bRow = (wn + col) * 64;

  for (int k0 = 0; k0 < K; k0 += 64) {
    __syncthreads();  // prior LDS reads done before overwrite
    gld_lds16(gA + k0,            &As[(size_t)tid * 8]);
    gld_lds16(gA + rowK + k0,     &As[2048 + (size_t)tid * 8]);
    gld_lds16(gA + 2 * rowK + k0, &As[4096 + (size_t)tid * 8]);
    gld_lds16(gA + 3 * rowK + k0, &As[6144 + (size_t)tid * 8]);
    gld_lds16(gB + k0,            &Bs[(size_t)tid * 8]);
    gld_lds16(gB + rowK + k0,     &Bs[2048 + (size_t)tid * 8]);
    gld_lds16(gB + 2 * rowK + k0, &Bs[4096 + (size_t)tid * 8]);
    gld_lds16(gB + 3 * rowK + k0, &Bs[6144 + (size_t)tid * 8]);
    __syncthreads();  // drains vmcnt -> staged data visible

#pragma unroll
    for (int kk = 0; kk < 2; ++kk) {
      int s = s0 ^ (kk * 32);  // slot XOR 4 chunks = 32 u16
      bf16x8 xf[4], wf[4];
#pragma unroll
      for (int t = 0; t < 4; ++t) {
        xf[t] = __builtin_bit_cast(bf16x8,
            *reinterpret_cast<u16x8*>(&As[aRow + t * 1024 + s]));
        wf[t] = __builtin_bit_cast(bf16x8,
            *reinterpret_cast<u16x8*>(&Bs[bRow + t * 1024 + s]));
      }
#pragma unroll
      for (int i = 0; i < 4; ++i)
#pragma unroll
        for (int j = 0; j < 4; ++j)
          acc[i][j] = __builtin_amdgcn_mfma_f32_16x16x32_bf16(
              wf[j], xf[i], acc[i][j], 0, 0, 0);
    }
  }

  // epilogue: lane holds m = m0+wm+i*16+col, n = n0+wn+j*16+quad*4+[0..3]
#pragma unroll
  for (int j = 0; j < 4; ++j) {
    int nn = n0 + wn + j * 16 + quad * 4;
    float4 b4 = *reinterpret_cast<const float4*>(&bias[nn]);
#pragma unroll
    for (int i = 0; i < 4; ++i) {
      int m = m0 + wm + i * 16 + col;
      u16x4 o;
      o.x = f2bf(elu1(acc[i][j][0] + b4.x));
      o.y = f2bf(elu1(acc[i][j][1] + b4.y));
      o.z = f2bf(elu1(acc[i][j][2] + b4.z));
      o.w = f2bf(elu1(acc[i][j][3] + b4.w));
      *reinterpret_cast<u16x4*>(&C[(long)m * N + nn]) = o;
    }
  }
}

// ---------------- fused L4: gate + softmax + expert heads + combine -------
__global__ __launch_bounds__(256) void final_combine_kernel(
    const u16* __restrict__ h3, const u16* __restrict__ W4t,
    const u16* __restrict__ gW4t, const float* __restrict__ eb4,
    const float* __restrict__ gb4, float* __restrict__ out) {
  const int H3 = 256;
  int tid = threadIdx.x;
  int lane = tid & 63;
  int w = tid >> 6;  // wave 0..3
  int col = lane & 15;
  int quad = lane >> 4;
  int r0 = blockIdx.x * 16;

  // ---- gate logits (every wave, same 16 rows) ----
  floatx4 g0 = {}, g1 = {};
  const u16* h3g = h3 + (long)E_EXP * B_SZ * H3;
#pragma unroll
  for (int k0 = 0; k0 < 256; k0 += 32) {
    bf16x8 a = ld_bf8(&h3g[(long)(r0 + col) * H3 + k0 + quad * 8]);
    bf16x8 b0 = ld_bf8(&gW4t[(long)col * H3 + k0 + quad * 8]);
    bf16x8 b1 = ld_bf8(&gW4t[(long)(16 + col) * H3 + k0 + quad * 8]);
    g0 = __builtin_amdgcn_mfma_f32_16x16x32_bf16(a, b0, g0, 0, 0, 0);
    g1 = __builtin_amdgcn_mfma_f32_16x16x32_bf16(a, b1, g1, 0, 0, 0);
  }

  // ---- softmax over 20 logits per row ----
  float w0[4], w1[4];
  float gbc0 = gb4[col];
  float gbc1 = (col < 4) ? gb4[16 + col] : 0.f;
#pragma unroll
  for (int r = 0; r < 4; ++r) {
    float v0 = g0[r] + gbc0;
    float v1 = (col < 4) ? (g1[r] + gbc1) : -1e30f;
    float m = fmaxf(v0, v1);
#pragma unroll
    for (int s = 1; s < 16; s <<= 1) m = fmaxf(m, __shfl_xor(m, s, 64));
    float e0 = __expf(v0 - m);
    float e1 = (col < 4) ? __expf(v1 - m) : 0.f;
    float ssum = e0 + e1;
#pragma unroll
    for (int s = 1; s < 16; s <<= 1) ssum += __shfl_xor(ssum, s, 64);
    w0[r] = e0 / ssum;
    w1[r] = e1 / ssum;
  }

  // ---- this wave's experts: w, w+4, w+8, w+12, w+16 ----
  floatx4 o0 = {}, o1 = {};
  for (int e = w; e < E_EXP; e += 4) {
    floatx4 a0 = {}, a1 = {};
    const u16* he = h3 + (long)e * B_SZ * H3;
    const u16* we = W4t + (long)e * 32 * H3;
#pragma unroll
    for (int k0 = 0; k0 < 256; k0 += 32) {
      bf16x8 a = ld_bf8(&he[(long)(r0 + col) * H3 + k0 + quad * 8]);
      bf16x8 b0 = ld_bf8(&we[(long)col * H3 + k0 + quad * 8]);
      bf16x8 b1 = ld_bf8(&we[(long)(16 + col) * H3 + k0 + quad * 8]);
      a0 = __builtin_amdgcn_mfma_f32_16x16x32_bf16(a, b0, a0, 0, 0, 0);
      a1 = __builtin_amdgcn_mfma_f32_16x16x32_bf16(a, b1, a1, 0, 0, 0);
    }
    float be0 = eb4[e * 32 + col];
    float be1 = eb4[e * 32 + 16 + col];
    int src = (lane & 48) + (e & 15);
#pragma unroll
    for (int r = 0; r < 4; ++r) {
      float wr = __shfl((e < 16) ? w0[r] : w1[r], src, 64);
      o0[r] += wr * (a0[r] + be0);
      o1[r] += wr * (a1[r] + be1);
    }
  }

  // ---- cross-wave reduce in LDS ----
  __shared__ float red[3][64][8];
  if (w > 0) {
#pragma unroll
    for (int r = 0; r < 4; ++r) {
      red[w - 1][lane][r] = o0[r];
      red[w - 1][lane][4 + r] = o1[r];
    }
  }
  __syncthreads();
  if (w == 0) {
#pragma unroll
    for (int ww = 0; ww < 3; ++ww)
#pragma unroll
      for (int r = 0; r < 4; ++r) {
        o0[r] += red[ww][lane][r];
        o1[r] += red[ww][lane][4 + r];
      }
#pragma unroll
    for (int r = 0; r < 4; ++r) {
      int row = r0 + quad * 4 + r;
      out[(long)row * 32 + col] = o0[r];
      out[(long)row * 32 + 16 + col] = o1[r];
    }
  }
}

// ---------------- host launch ----------------

static inline size_t align256(size_t x) { return (x + 255) & ~(size_t)255; }

extern "C" void kernel_launch(void* const* d_in, const int* in_sizes, int n_in,
                              void* d_out, int out_size, void* d_ws,
                              size_t ws_size, hipStream_t stream) {
  const float* obs = (const float*)d_in[0];
  const float* eW1 = (const float*)d_in[1];
  const float* eb1 = (const float*)d_in[2];
  const float* eW2 = (const float*)d_in[3];
  const float* eb2 = (const float*)d_in[4];
  const float* eW3 = (const float*)d_in[5];
  const float* eb3 = (const float*)d_in[6];
  const float* eW4 = (const float*)d_in[7];
  const float* eb4 = (const float*)d_in[8];
  const float* gW1 = (const float*)d_in[9];
  const float* gb1 = (const float*)d_in[10];
  const float* gW2 = (const float*)d_in[11];
  const float* gb2 = (const float*)d_in[12];
  const float* gW3 = (const float*)d_in[13];
  const float* gb3 = (const float*)d_in[14];
  const float* gW4 = (const float*)d_in[15];
  const float* gb4 = (const float*)d_in[16];
  float* out = (float*)d_out;
  char* ws = (char*)d_ws;

  // fixed workspace region
  size_t off = 0;
  size_t OFF_OBS = off;  off = align256(off + (size_t)B_SZ * 512 * 2);
  size_t OFF_W1T = off;  off = align256(off + (size_t)NE * 1024 * 512 * 2);
  size_t OFF_W2T = off;  off = align256(off + (size_t)NE * 512 * 1024 * 2);
  size_t OFF_W3T = off;  off = align256(off + (size_t)NE * 256 * 512 * 2);
  size_t OFF_W4T = off;  off = align256(off + (size_t)E_EXP * 32 * 256 * 2);
  size_t OFF_GW4T = off; off = align256(off + (size_t)32 * 256 * 2);
  size_t OFF_B1 = off;   off = align256(off + (size_t)NE * 1024 * 4);
  size_t OFF_B2 = off;   off = align256(off + (size_t)NE * 512 * 4);
  size_t OFF_B3 = off;   off = align256(off + (size_t)NE * 256 * 4);
  size_t OFF_H3 = off;   off = align256(off + (size_t)NE * B_SZ * 256 * 2);

  // adaptive batch-chunked h1/h2: every dispatch covers all 21 experts
  int chunk = B_SZ;
  size_t OFF_H1 = off;
  while (chunk > 512) {
    size_t need = (size_t)NE * chunk * 1024 * 2 + (size_t)NE * chunk * 512 * 2;
    if (OFF_H1 + need <= ws_size) break;
    chunk >>= 1;
  }
  size_t OFF_H2 = align256(OFF_H1 + (size_t)NE * chunk * 1024 * 2);

  u16* obs_bf = (u16*)(ws + OFF_OBS);
  u16* W1t = (u16*)(ws + OFF_W1T);
  u16* W2t = (u16*)(ws + OFF_W2T);
  u16* W3t = (u16*)(ws + OFF_W3T);
  u16* W4t = (u16*)(ws + OFF_W4T);
  u16* gW4t = (u16*)(ws + OFF_GW4T);
  float* b1 = (float*)(ws + OFF_B1);
  float* b2 = (float*)(ws + OFF_B2);
  float* b3 = (float*)(ws + OFF_B3);
  u16* h3 = (u16*)(ws + OFF_H3);
  u16* h1 = (u16*)(ws + OFF_H1);
  u16* h2 = (u16*)(ws + OFF_H2);

  // --- prep: obs convert + bias concat (1), all transposes (1) ---
  prep_small_kernel<<<2048 + (NE * 1792 + 255) / 256, 256, 0, stream>>>(
      obs, obs_bf, eb1, gb1, eb2, gb2, eb3, gb3, b1, b2, b3);
  transpose_all_kernel<<<TRANS_BLOCKS, 256, 0, stream>>>(
      eW1, gW1, eW2, gW2, eW3, gW3, eW4, gW4, W1t, W2t, W3t, W4t, gW4t);

  int ntm = chunk / BM;
  // --- trunk layers 1..3, batch-chunked, XCD-clustered 1-D grids ---
  for (int bc = 0; bc < B_SZ; bc += chunk) {
    gemm_bias_elu_kernel<<<NE * 8 * ntm, 256, 0, stream>>>(
        obs_bf + (size_t)bc * 512, 0L,
        W1t, (long)1024 * 512,
        b1, 1024L,
        h1, (long)chunk * 1024, chunk, 1024, 512, 8, ntm);
    gemm_bias_elu_kernel<<<NE * 4 * ntm, 256, 0, stream>>>(
        h1, (long)chunk * 1024,
        W2t, (long)512 * 1024,
        b2, 512L,
        h2, (long)chunk * 512, chunk, 512, 1024, 4, ntm);
    gemm_bias_elu_kernel<<<NE * 2 * ntm, 256, 0, stream>>>(
        h2, (long)chunk * 512,
        W3t, (long)256 * 512,
        b3, 256L,
        h3 + (size_t)bc * 256, (long)B_SZ * 256, chunk, 256, 512, 2, ntm);
  }

  // --- fused layer-4 + softmax + combine ---
  final_combine_kernel<<<B_SZ / 16, 256, 0, stream>>>(h3, W4t, gW4t, eb4, gb4,
                                                      out);
}

// Round 6
// 497.921 us; speedup vs baseline: 1.0602x; 1.0125x over previous
//
#include <hip/hip_runtime.h>

#define B_SZ 4096
#define E_EXP 20
#define NE 21  // 20 experts + gate share the trunk

typedef unsigned short u16;
typedef __bf16 bf16x8 __attribute__((ext_vector_type(8)));
typedef u16 u16x8 __attribute__((ext_vector_type(8)));
typedef u16 u16x4 __attribute__((ext_vector_type(4)));
typedef float floatx4 __attribute__((ext_vector_type(4)));

static __device__ __forceinline__ u16 f2bf(float f) {
  unsigned u = __builtin_bit_cast(unsigned, f);
  u += 0x7fffu + ((u >> 16) & 1u);  // RNE
  return (u16)(u >> 16);
}

static __device__ __forceinline__ float elu1(float v) {
  return v > 0.f ? v : (__expf(v) - 1.f);
}

static __device__ __forceinline__ bf16x8 ld_bf8(const u16* p) {
  u16x8 v = *reinterpret_cast<const u16x8*>(p);
  return __builtin_bit_cast(bf16x8, v);
}

// async global->LDS DMA, 16B per lane. LDS dest is wave-uniform base +
// lane*16 — lds ptr must be linear in thread order (no padding!).
static __device__ __forceinline__ void gld_lds16(const u16* g, u16* l) {
  __builtin_amdgcn_global_load_lds(
      (const __attribute__((address_space(1))) unsigned int*)g,
      (__attribute__((address_space(3))) unsigned int*)l, 16, 0, 0);
}

// ---------------- prep: obs convert + bias concat, one dispatch ----------

__global__ void prep_small_kernel(
    const float* __restrict__ obs, u16* __restrict__ obs_bf,
    const float* __restrict__ eb1, const float* __restrict__ gb1,
    const float* __restrict__ eb2, const float* __restrict__ gb2,
    const float* __restrict__ eb3, const float* __restrict__ gb3,
    float* __restrict__ b1, float* __restrict__ b2, float* __restrict__ b3) {
  int bid = blockIdx.x;
  if (bid < 2048) {  // obs: B_SZ*512 floats, 4/thread
    int i = (bid * 256 + threadIdx.x) * 4;
    float4 v = *reinterpret_cast<const float4*>(obs + i);
    u16x4 o;
    o.x = f2bf(v.x); o.y = f2bf(v.y); o.z = f2bf(v.z); o.w = f2bf(v.w);
    *reinterpret_cast<u16x4*>(obs_bf + i) = o;
  } else {
    int i = (bid - 2048) * 256 + threadIdx.x;
    const int S1 = NE * 1024, S2 = NE * 512, S3 = NE * 256;
    if (i < S1) {
      b1[i] = (i < E_EXP * 1024) ? eb1[i] : gb1[i - E_EXP * 1024];
    } else if (i < S1 + S2) {
      int j = i - S1;
      b2[j] = (j < E_EXP * 512) ? eb2[j] : gb2[j - E_EXP * 512];
    } else if (i < S1 + S2 + S3) {
      int j = i - S1 - S2;
      b3[j] = (j < E_EXP * 256) ? eb3[j] : gb3[j - E_EXP * 256];
    }
  }
}

// ---------------- all weight transposes, one job-table dispatch ----------
#define TRANS_BLOCKS 6132

__global__ __launch_bounds__(256) void transpose_all_kernel(
    const float* __restrict__ eW1, const float* __restrict__ gW1,
    const float* __restrict__ eW2, const float* __restrict__ gW2,
    const float* __restrict__ eW3, const float* __restrict__ gW3,
    const float* __restrict__ eW4, const float* __restrict__ gW4,
    u16* __restrict__ W1t, u16* __restrict__ W2t, u16* __restrict__ W3t,
    u16* __restrict__ W4t, u16* __restrict__ gW4t) {
  int f = blockIdx.x;
  const float *srcE, *srcG;
  u16* dstBase;
  int rem, K, N, Nout, kxt, tpm, nm;
  if (f < 2688) {
    rem = f;        srcE = eW1; srcG = gW1; dstBase = W1t;
    K = 512;  N = 1024; Nout = 1024; kxt = 8;  tpm = 128; nm = 20;
  } else if (f < 5376) {
    rem = f - 2688; srcE = eW2; srcG = gW2; dstBase = W2t;
    K = 1024; N = 512;  Nout = 512;  kxt = 16; tpm = 128; nm = 20;
  } else if (f < 6048) {
    rem = f - 5376; srcE = eW3; srcG = gW3; dstBase = W3t;
    K = 512;  N = 256;  Nout = 256;  kxt = 8;  tpm = 32;  nm = 20;
  } else if (f < 6128) {
    rem = f - 6048; srcE = eW4; srcG = nullptr; dstBase = W4t;
    K = 256;  N = 32;   Nout = 32;   kxt = 4;  tpm = 4;   nm = 99;
  } else {
    rem = f - 6128; srcE = gW4; srcG = nullptr; dstBase = gW4t;
    K = 256;  N = 20;   Nout = 32;   kxt = 4;  tpm = 4;   nm = 99;
  }
  int mat = rem / tpm;
  int t = rem % tpm;
  const float* src = (mat < nm) ? (srcE + (long)mat * K * N) : srcG;
  u16* dst = dstBase + (long)mat * Nout * K;
  int kbase = (t % kxt) * 64;
  int nbase = (t / kxt) * 64;

  __shared__ float tl[64][65];
  int tid = threadIdx.x;
  int kk = tid >> 4;        // 0..15
  int n4 = (tid & 15) * 4;  // 0..60
#pragma unroll
  for (int p = 0; p < 4; ++p) {
    int k = kbase + p * 16 + kk;  // always < K (grid exact)
    int n = nbase + n4;
    float4 v = make_float4(0.f, 0.f, 0.f, 0.f);
    if (n + 3 < N) {
      v = *reinterpret_cast<const float4*>(&src[(long)k * N + n]);
    } else {
      float* vp = &v.x;
      for (int j = 0; j < 4; ++j)
        if (n + j < N) vp[j] = src[(long)k * N + n + j];
    }
    tl[p * 16 + kk][n4 + 0] = v.x;
    tl[p * 16 + kk][n4 + 1] = v.y;
    tl[p * 16 + kk][n4 + 2] = v.z;
    tl[p * 16 + kk][n4 + 3] = v.w;
  }
  __syncthreads();

  int kk8 = (tid & 7) * 8;
#pragma unroll
  for (int p = 0; p < 2; ++p) {
    int ln = p * 32 + (tid >> 3);  // 0..63
    int n = nbase + ln;
    if (n < Nout) {
      u16x8 o;
#pragma unroll
      for (int j = 0; j < 8; ++j) o[j] = f2bf(tl[kk8 + j][ln]);
      *reinterpret_cast<u16x8*>(&dst[(long)n * K + kbase + kk8]) = o;
    }
  }
}

// ---------------- grouped GEMM + bias + ELU ----------------
// C[M,N] = elu(A[M,K] @ Wt[N,K]^T + bias), bf16 in/out, fp32 accumulate.
// 128x128 tile, BK=64, global_load_lds staging, XCD-clustered decode,
// 128B-row LDS + 8-slot XOR swizzle (R5: bank conflicts 5.5M -> 0).
//
// R6: T3-minimum double-buffered pipeline (guide §5.5, m248 +10%):
//   stage(t+1) into the OTHER buffer is issued BEFORE compute(t), so the
//   global->LDS DMA latency (~200-900 cyc) overlaps the ds_read+MFMA
//   phase; ONE __syncthreads per K-step (its vmcnt(0)+lgkmcnt(0) drain is
//   the single wait, placed AFTER compute). Buffers are DISTINCT static
//   __shared__ arrays referenced by NAME (macros, not pointer params) so
//   the waitcnt pass's alias analysis can prove ds_reads of buf0 don't
//   alias the in-flight DMA into buf1 and skip a conservative vmcnt(0)
//   drain before the reads (R1-R3 lesson). K is always a multiple of 128
//   here (512/1024/512) -> clean 2x-unrolled ping-pong.

#define BM 128
#define BN 128

__global__ __launch_bounds__(256) void gemm_bias_elu_kernel(
    const u16* __restrict__ A_base, long a_estride,
    const u16* __restrict__ Wt_base, long w_estride,
    const float* __restrict__ bias_base, long b_estride,
    u16* __restrict__ C_base, long c_estride,
    int M, int N, int K, int ntn, int ntm) {
  // XCD-clustered decode (gridDim.x divisible by 8)
  int per = gridDim.x >> 3;
  int wid = (blockIdx.x & 7) * per + (blockIdx.x >> 3);
  int tpe = ntn * ntm;
  int e = wid / tpe;
  int rem = wid - e * tpe;
  int mt = rem / ntn;        // m-tile (outer within expert)
  int nt = rem - mt * ntn;   // n-tile (inner -> A-tile reuse in time)
  int m0 = mt * BM;
  int n0 = nt * BN;

  const u16* A = A_base + (long)e * a_estride;
  const u16* Wt = Wt_base + (long)e * w_estride;
  const float* bias = bias_base + (long)e * b_estride;
  u16* C = C_base + (long)e * c_estride;

  // [row][64 k-elems] = 128B rows; 16KB each; dual buffers = 64KB
  __shared__ u16 As0[BM * 64];
  __shared__ u16 As1[BM * 64];
  __shared__ u16 Bs0[BN * 64];
  __shared__ u16 Bs1[BN * 64];

  int tid = threadIdx.x;
  int lane = tid & 63;
  int w = tid >> 6;            // wave 0..3 in 2x2
  int wm = (w >> 1) * 64;
  int wn = (w & 1) * 64;
  int col = lane & 15;
  int quad = lane >> 4;

  floatx4 acc[4][4] = {};

  // staging: thread -> (row = tid>>3 within 32-row group, slot = tid&7),
  // global chunk pre-swizzled: (tid&7) ^ ((tid>>3)&7)
  int srow = tid >> 3;                             // 0..31
  int gchunk = (tid & 7) ^ (srow & 7);
  const u16* gA = &A[(long)(m0 + srow) * K + gchunk * 8];
  const u16* gB = &Wt[(long)(n0 + srow) * K + gchunk * 8];
  long rowK = (long)32 * K;                        // 32 rows per instruction

  // read: slot s(kk) = (kk*4 + quad) ^ (col&7); row&7==col&7 cancels the
  // staging XOR -> identical data, conflict-free banking (R5 verified).
  int s0 = (quad ^ (col & 7)) * 8;                 // u16 offset of 16B slot
  int aRow = (wm + col) * 64;
  int bRow = (wn + col) * 64;

#define STAGE(Asb, Bsb, k0)                                   \
  do {                                                        \
    gld_lds16(gA + (k0),            &Asb[(size_t)tid * 8]);   \
    gld_lds16(gA + rowK + (k0),     &Asb[2048 + (size_t)tid * 8]); \
    gld_lds16(gA + 2 * rowK + (k0), &Asb[4096 + (size_t)tid * 8]); \
    gld_lds16(gA + 3 * rowK + (k0), &Asb[6144 + (size_t)tid * 8]); \
    gld_lds16(gB + (k0),            &Bsb[(size_t)tid * 8]);   \
    gld_lds16(gB + rowK + (k0),     &Bsb[2048 + (size_t)tid * 8]); \
    gld_lds16(gB + 2 * rowK + (k0), &Bsb[4096 + (size_t)tid * 8]); \
    gld_lds16(gB + 3 * rowK + (k0), &Bsb[6144 + (size_t)tid * 8]); \
  } while (0)

#define COMPUTE(Asb, Bsb)                                               \
  do {                                                                  \
    _Pragma("unroll")                                                   \
    for (int kk = 0; kk < 2; ++kk) {                                    \
      int s = s0 ^ (kk * 32);                                           \
      bf16x8 xf[4], wf[4];                                              \
      _Pragma("unroll")                                                 \
      for (int t4 = 0; t4 < 4; ++t4) {                                  \
        xf[t4] = __builtin_bit_cast(bf16x8,                             \
            *reinterpret_cast<const u16x8*>(&Asb[aRow + t4 * 1024 + s])); \
        wf[t4] = __builtin_bit_cast(bf16x8,                             \
            *reinterpret_cast<const u16x8*>(&Bsb[bRow + t4 * 1024 + s])); \
      }                                                                 \
      _Pragma("unroll")                                                 \
      for (int i = 0; i < 4; ++i)                                       \
        _Pragma("unroll")                                               \
        for (int j = 0; j < 4; ++j)                                     \
          acc[i][j] = __builtin_amdgcn_mfma_f32_16x16x32_bf16(          \
              wf[j], xf[i], acc[i][j], 0, 0, 0);                        \
    }                                                                   \
  } while (0)

  // prologue: tile 0 into buf0
  STAGE(As0, Bs0, 0);
  __syncthreads();  // drain prologue DMA

  for (int k0 = 0; k0 < K; k0 += 128) {
    // even tile: prefetch buf1, compute buf0
    if (k0 + 64 < K) STAGE(As1, Bs1, k0 + 64);
    COMPUTE(As0, Bs0);
    __syncthreads();  // drains vmcnt (buf1 DMA) + lgkm; WAR for buf0
    // odd tile: prefetch buf0, compute buf1
    if (k0 + 128 < K) STAGE(As0, Bs0, k0 + 128);
    COMPUTE(As1, Bs1);
    __syncthreads();  // drains vmcnt (buf0 DMA) + lgkm; WAR for buf1
  }
#undef STAGE
#undef COMPUTE

  // epilogue: lane holds m = m0+wm+i*16+col, n = n0+wn+j*16+quad*4+[0..3]
#pragma unroll
  for (int j = 0; j < 4; ++j) {
    int nn = n0 + wn + j * 16 + quad * 4;
    float4 b4 = *reinterpret_cast<const float4*>(&bias[nn]);
#pragma unroll
    for (int i = 0; i < 4; ++i) {
      int m = m0 + wm + i * 16 + col;
      u16x4 o;
      o.x = f2bf(elu1(acc[i][j][0] + b4.x));
      o.y = f2bf(elu1(acc[i][j][1] + b4.y));
      o.z = f2bf(elu1(acc[i][j][2] + b4.z));
      o.w = f2bf(elu1(acc[i][j][3] + b4.w));
      *reinterpret_cast<u16x4*>(&C[(long)m * N + nn]) = o;
    }
  }
}

// ---------------- fused L4: gate + softmax + expert heads + combine -------
__global__ __launch_bounds__(256) void final_combine_kernel(
    const u16* __restrict__ h3, const u16* __restrict__ W4t,
    const u16* __restrict__ gW4t, const float* __restrict__ eb4,
    const float* __restrict__ gb4, float* __restrict__ out) {
  const int H3 = 256;
  int tid = threadIdx.x;
  int lane = tid & 63;
  int w = tid >> 6;  // wave 0..3
  int col = lane & 15;
  int quad = lane >> 4;
  int r0 = blockIdx.x * 16;

  // ---- gate logits (every wave, same 16 rows) ----
  floatx4 g0 = {}, g1 = {};
  const u16* h3g = h3 + (long)E_EXP * B_SZ * H3;
#pragma unroll
  for (int k0 = 0; k0 < 256; k0 += 32) {
    bf16x8 a = ld_bf8(&h3g[(long)(r0 + col) * H3 + k0 + quad * 8]);
    bf16x8 b0 = ld_bf8(&gW4t[(long)col * H3 + k0 + quad * 8]);
    bf16x8 b1 = ld_bf8(&gW4t[(long)(16 + col) * H3 + k0 + quad * 8]);
    g0 = __builtin_amdgcn_mfma_f32_16x16x32_bf16(a, b0, g0, 0, 0, 0);
    g1 = __builtin_amdgcn_mfma_f32_16x16x32_bf16(a, b1, g1, 0, 0, 0);
  }

  // ---- softmax over 20 logits per row ----
  float w0[4], w1[4];
  float gbc0 = gb4[col];
  float gbc1 = (col < 4) ? gb4[16 + col] : 0.f;
#pragma unroll
  for (int r = 0; r < 4; ++r) {
    float v0 = g0[r] + gbc0;
    float v1 = (col < 4) ? (g1[r] + gbc1) : -1e30f;
    float m = fmaxf(v0, v1);
#pragma unroll
    for (int s = 1; s < 16; s <<= 1) m = fmaxf(m, __shfl_xor(m, s, 64));
    float e0 = __expf(v0 - m);
    float e1 = (col < 4) ? __expf(v1 - m) : 0.f;
    float ssum = e0 + e1;
#pragma unroll
    for (int s = 1; s < 16; s <<= 1) ssum += __shfl_xor(ssum, s, 64);
    w0[r] = e0 / ssum;
    w1[r] = e1 / ssum;
  }

  // ---- this wave's experts: w, w+4, w+8, w+12, w+16 ----
  floatx4 o0 = {}, o1 = {};
  for (int e = w; e < E_EXP; e += 4) {
    floatx4 a0 = {}, a1 = {};
    const u16* he = h3 + (long)e * B_SZ * H3;
    const u16* we = W4t + (long)e * 32 * H3;
#pragma unroll
    for (int k0 = 0; k0 < 256; k0 += 32) {
      bf16x8 a = ld_bf8(&he[(long)(r0 + col) * H3 + k0 + quad * 8]);
      bf16x8 b0 = ld_bf8(&we[(long)col * H3 + k0 + quad * 8]);
      bf16x8 b1 = ld_bf8(&we[(long)(16 + col) * H3 + k0 + quad * 8]);
      a0 = __builtin_amdgcn_mfma_f32_16x16x32_bf16(a, b0, a0, 0, 0, 0);
      a1 = __builtin_amdgcn_mfma_f32_16x16x32_bf16(a, b1, a1, 0, 0, 0);
    }
    float be0 = eb4[e * 32 + col];
    float be1 = eb4[e * 32 + 16 + col];
    int src = (lane & 48) + (e & 15);
#pragma unroll
    for (int r = 0; r < 4; ++r) {
      float wr = __shfl((e < 16) ? w0[r] : w1[r], src, 64);
      o0[r] += wr * (a0[r] + be0);
      o1[r] += wr * (a1[r] + be1);
    }
  }

  // ---- cross-wave reduce in LDS ----
  __shared__ float red[3][64][8];
  if (w > 0) {
#pragma unroll
    for (int r = 0; r < 4; ++r) {
      red[w - 1][lane][r] = o0[r];
      red[w - 1][lane][4 + r] = o1[r];
    }
  }
  __syncthreads();
  if (w == 0) {
#pragma unroll
    for (int ww = 0; ww < 3; ++ww)
#pragma unroll
      for (int r = 0; r < 4; ++r) {
        o0[r] += red[ww][lane][r];
        o1[r] += red[ww][lane][4 + r];
      }
#pragma unroll
    for (int r = 0; r < 4; ++r) {
      int row = r0 + quad * 4 + r;
      out[(long)row * 32 + col] = o0[r];
      out[(long)row * 32 + 16 + col] = o1[r];
    }
  }
}

// ---------------- host launch ----------------

static inline size_t align256(size_t x) { return (x + 255) & ~(size_t)255; }

extern "C" void kernel_launch(void* const* d_in, const int* in_sizes, int n_in,
                              void* d_out, int out_size, void* d_ws,
                              size_t ws_size, hipStream_t stream) {
  const float* obs = (const float*)d_in[0];
  const float* eW1 = (const float*)d_in[1];
  const float* eb1 = (const float*)d_in[2];
  const float* eW2 = (const float*)d_in[3];
  const float* eb2 = (const float*)d_in[4];
  const float* eW3 = (const float*)d_in[5];
  const float* eb3 = (const float*)d_in[6];
  const float* eW4 = (const float*)d_in[7];
  const float* eb4 = (const float*)d_in[8];
  const float* gW1 = (const float*)d_in[9];
  const float* gb1 = (const float*)d_in[10];
  const float* gW2 = (const float*)d_in[11];
  const float* gb2 = (const float*)d_in[12];
  const float* gW3 = (const float*)d_in[13];
  const float* gb3 = (const float*)d_in[14];
  const float* gW4 = (const float*)d_in[15];
  const float* gb4 = (const float*)d_in[16];
  float* out = (float*)d_out;
  char* ws = (char*)d_ws;

  // fixed workspace region
  size_t off = 0;
  size_t OFF_OBS = off;  off = align256(off + (size_t)B_SZ * 512 * 2);
  size_t OFF_W1T = off;  off = align256(off + (size_t)NE * 1024 * 512 * 2);
  size_t OFF_W2T = off;  off = align256(off + (size_t)NE * 512 * 1024 * 2);
  size_t OFF_W3T = off;  off = align256(off + (size_t)NE * 256 * 512 * 2);
  size_t OFF_W4T = off;  off = align256(off + (size_t)E_EXP * 32 * 256 * 2);
  size_t OFF_GW4T = off; off = align256(off + (size_t)32 * 256 * 2);
  size_t OFF_B1 = off;   off = align256(off + (size_t)NE * 1024 * 4);
  size_t OFF_B2 = off;   off = align256(off + (size_t)NE * 512 * 4);
  size_t OFF_B3 = off;   off = align256(off + (size_t)NE * 256 * 4);
  size_t OFF_H3 = off;   off = align256(off + (size_t)NE * B_SZ * 256 * 2);

  // adaptive batch-chunked h1/h2: every dispatch covers all 21 experts
  int chunk = B_SZ;
  size_t OFF_H1 = off;
  while (chunk > 512) {
    size_t need = (size_t)NE * chunk * 1024 * 2 + (size_t)NE * chunk * 512 * 2;
    if (OFF_H1 + need <= ws_size) break;
    chunk >>= 1;
  }
  size_t OFF_H2 = align256(OFF_H1 + (size_t)NE * chunk * 1024 * 2);

  u16* obs_bf = (u16*)(ws + OFF_OBS);
  u16* W1t = (u16*)(ws + OFF_W1T);
  u16* W2t = (u16*)(ws + OFF_W2T);
  u16* W3t = (u16*)(ws + OFF_W3T);
  u16* W4t = (u16*)(ws + OFF_W4T);
  u16* gW4t = (u16*)(ws + OFF_GW4T);
  float* b1 = (float*)(ws + OFF_B1);
  float* b2 = (float*)(ws + OFF_B2);
  float* b3 = (float*)(ws + OFF_B3);
  u16* h3 = (u16*)(ws + OFF_H3);
  u16* h1 = (u16*)(ws + OFF_H1);
  u16* h2 = (u16*)(ws + OFF_H2);

  // --- prep: obs convert + bias concat (1), all transposes (1) ---
  prep_small_kernel<<<2048 + (NE * 1792 + 255) / 256, 256, 0, stream>>>(
      obs, obs_bf, eb1, gb1, eb2, gb2, eb3, gb3, b1, b2, b3);
  transpose_all_kernel<<<TRANS_BLOCKS, 256, 0, stream>>>(
      eW1, gW1, eW2, gW2, eW3, gW3, eW4, gW4, W1t, W2t, W3t, W4t, gW4t);

  int ntm = chunk / BM;
  // --- trunk layers 1..3, batch-chunked, XCD-clustered 1-D grids ---
  for (int bc = 0; bc < B_SZ; bc += chunk) {
    gemm_bias_elu_kernel<<<NE * 8 * ntm, 256, 0, stream>>>(
        obs_bf + (size_t)bc * 512, 0L,
        W1t, (long)1024 * 512,
        b1, 1024L,
        h1, (long)chunk * 1024, chunk, 1024, 512, 8, ntm);
    gemm_bias_elu_kernel<<<NE * 4 * ntm, 256, 0, stream>>>(
        h1, (long)chunk * 1024,
        W2t, (long)512 * 1024,
        b2, 512L,
        h2, (long)chunk * 512, chunk, 512, 1024, 4, ntm);
    gemm_bias_elu_kernel<<<NE * 2 * ntm, 256, 0, stream>>>(
        h2, (long)chunk * 512,
        W3t, (long)256 * 512,
        b3, 256L,
        h3 + (size_t)bc * 256, (long)B_SZ * 256, chunk, 256, 512, 2, ntm);
  }

  // --- fused layer-4 + softmax + combine ---
  final_combine_kernel<<<B_SZ / 16, 256, 0, stream>>>(h3, W4t, gW4t, eb4, gb4,
                                                      out);
}

// Round 7
// 472.381 us; speedup vs baseline: 1.1175x; 1.0541x over previous
//
#include <hip/hip_runtime.h>

#define B_SZ 4096
#define E_EXP 20
#define NE 21  // 20 experts + gate share the trunk

typedef unsigned short u16;
typedef __bf16 bf16x8 __attribute__((ext_vector_type(8)));
typedef u16 u16x8 __attribute__((ext_vector_type(8)));
typedef u16 u16x4 __attribute__((ext_vector_type(4)));
typedef float floatx4 __attribute__((ext_vector_type(4)));

static __device__ __forceinline__ u16 f2bf(float f) {
  unsigned u = __builtin_bit_cast(unsigned, f);
  u += 0x7fffu + ((u >> 16) & 1u);  // RNE
  return (u16)(u >> 16);
}

static __device__ __forceinline__ float elu1(float v) {
  return v > 0.f ? v : (__expf(v) - 1.f);
}

static __device__ __forceinline__ bf16x8 ld_bf8(const u16* p) {
  u16x8 v = *reinterpret_cast<const u16x8*>(p);
  return __builtin_bit_cast(bf16x8, v);
}

// async global->LDS DMA, 16B per lane. LDS dest is wave-uniform base +
// lane*16 — lds ptr must be linear in thread order (no padding!).
static __device__ __forceinline__ void gld_lds16(const u16* g, u16* l) {
  __builtin_amdgcn_global_load_lds(
      (const __attribute__((address_space(1))) unsigned int*)g,
      (__attribute__((address_space(3))) unsigned int*)l, 16, 0, 0);
}

// ---------------- prep: obs convert + bias concat, one dispatch ----------

__global__ void prep_small_kernel(
    const float* __restrict__ obs, u16* __restrict__ obs_bf,
    const float* __restrict__ eb1, const float* __restrict__ gb1,
    const float* __restrict__ eb2, const float* __restrict__ gb2,
    const float* __restrict__ eb3, const float* __restrict__ gb3,
    float* __restrict__ b1, float* __restrict__ b2, float* __restrict__ b3) {
  int bid = blockIdx.x;
  if (bid < 2048) {  // obs: B_SZ*512 floats, 4/thread
    int i = (bid * 256 + threadIdx.x) * 4;
    float4 v = *reinterpret_cast<const float4*>(obs + i);
    u16x4 o;
    o.x = f2bf(v.x); o.y = f2bf(v.y); o.z = f2bf(v.z); o.w = f2bf(v.w);
    *reinterpret_cast<u16x4*>(obs_bf + i) = o;
  } else {
    int i = (bid - 2048) * 256 + threadIdx.x;
    const int S1 = NE * 1024, S2 = NE * 512, S3 = NE * 256;
    if (i < S1) {
      b1[i] = (i < E_EXP * 1024) ? eb1[i] : gb1[i - E_EXP * 1024];
    } else if (i < S1 + S2) {
      int j = i - S1;
      b2[j] = (j < E_EXP * 512) ? eb2[j] : gb2[j - E_EXP * 512];
    } else if (i < S1 + S2 + S3) {
      int j = i - S1 - S2;
      b3[j] = (j < E_EXP * 256) ? eb3[j] : gb3[j - E_EXP * 256];
    }
  }
}

// ---------------- all weight transposes, one job-table dispatch ----------
#define TRANS_BLOCKS 6132

__global__ __launch_bounds__(256) void transpose_all_kernel(
    const float* __restrict__ eW1, const float* __restrict__ gW1,
    const float* __restrict__ eW2, const float* __restrict__ gW2,
    const float* __restrict__ eW3, const float* __restrict__ gW3,
    const float* __restrict__ eW4, const float* __restrict__ gW4,
    u16* __restrict__ W1t, u16* __restrict__ W2t, u16* __restrict__ W3t,
    u16* __restrict__ W4t, u16* __restrict__ gW4t) {
  int f = blockIdx.x;
  const float *srcE, *srcG;
  u16* dstBase;
  int rem, K, N, Nout, kxt, tpm, nm;
  if (f < 2688) {
    rem = f;        srcE = eW1; srcG = gW1; dstBase = W1t;
    K = 512;  N = 1024; Nout = 1024; kxt = 8;  tpm = 128; nm = 20;
  } else if (f < 5376) {
    rem = f - 2688; srcE = eW2; srcG = gW2; dstBase = W2t;
    K = 1024; N = 512;  Nout = 512;  kxt = 16; tpm = 128; nm = 20;
  } else if (f < 6048) {
    rem = f - 5376; srcE = eW3; srcG = gW3; dstBase = W3t;
    K = 512;  N = 256;  Nout = 256;  kxt = 8;  tpm = 32;  nm = 20;
  } else if (f < 6128) {
    rem = f - 6048; srcE = eW4; srcG = nullptr; dstBase = W4t;
    K = 256;  N = 32;   Nout = 32;   kxt = 4;  tpm = 4;   nm = 99;
  } else {
    rem = f - 6128; srcE = gW4; srcG = nullptr; dstBase = gW4t;
    K = 256;  N = 20;   Nout = 32;   kxt = 4;  tpm = 4;   nm = 99;
  }
  int mat = rem / tpm;
  int t = rem % tpm;
  const float* src = (mat < nm) ? (srcE + (long)mat * K * N) : srcG;
  u16* dst = dstBase + (long)mat * Nout * K;
  int kbase = (t % kxt) * 64;
  int nbase = (t / kxt) * 64;

  __shared__ float tl[64][65];
  int tid = threadIdx.x;
  int kk = tid >> 4;        // 0..15
  int n4 = (tid & 15) * 4;  // 0..60
#pragma unroll
  for (int p = 0; p < 4; ++p) {
    int k = kbase + p * 16 + kk;  // always < K (grid exact)
    int n = nbase + n4;
    float4 v = make_float4(0.f, 0.f, 0.f, 0.f);
    if (n + 3 < N) {
      v = *reinterpret_cast<const float4*>(&src[(long)k * N + n]);
    } else {
      float* vp = &v.x;
      for (int j = 0; j < 4; ++j)
        if (n + j < N) vp[j] = src[(long)k * N + n + j];
    }
    tl[p * 16 + kk][n4 + 0] = v.x;
    tl[p * 16 + kk][n4 + 1] = v.y;
    tl[p * 16 + kk][n4 + 2] = v.z;
    tl[p * 16 + kk][n4 + 3] = v.w;
  }
  __syncthreads();

  int kk8 = (tid & 7) * 8;
#pragma unroll
  for (int p = 0; p < 2; ++p) {
    int ln = p * 32 + (tid >> 3);  // 0..63
    int n = nbase + ln;
    if (n < Nout) {
      u16x8 o;
#pragma unroll
      for (int j = 0; j < 8; ++j) o[j] = f2bf(tl[kk8 + j][ln]);
      *reinterpret_cast<u16x8*>(&dst[(long)n * K + kbase + kk8]) = o;
    }
  }
}

// ---------------- grouped GEMM + bias + ELU ----------------
// C[M,N] = elu(A[M,K] @ Wt[N,K]^T + bias), bf16 in/out, fp32 accumulate.
// R7: 128x64 tile for OCCUPANCY. R6 post-mortem: every pipe at ~25%,
// 8 waves/CU, dual-capped by VGPR (152 regs -> pow2 rounding -> 2
// waves/SIMD, m69) and LDS (64KB -> 2 blocks). Shrink to BN=64:
//   - wave tile 64x32 -> acc 4x2 = 32 AGPR; __launch_bounds__(256,4)
//     pins total regs <=128 -> 4 waves/SIMD bracket.
//   - LDS: A dbuf 2x16KB + B dbuf 2x8KB = 48KB -> 3 blocks/CU.
//   - => 12 waves/CU (37.5%), 1.9x current concurrency, in a regime
//     where time has tracked concurrency, not structure.
// Keeps: BK=64 dbuf ping-pong (distinct named __shared__ arrays),
// 128B-row LDS + 8-slot XOR swizzle (conflicts == 0, R5), gld_lds
// staging with pre-swizzled source, XCD-clustered decode.

#define BM 128
#define BN 64

__global__ __launch_bounds__(256, 4) void gemm_bias_elu_kernel(
    const u16* __restrict__ A_base, long a_estride,
    const u16* __restrict__ Wt_base, long w_estride,
    const float* __restrict__ bias_base, long b_estride,
    u16* __restrict__ C_base, long c_estride,
    int M, int N, int K, int ntn, int ntm) {
  // XCD-clustered decode (gridDim.x divisible by 8)
  int per = gridDim.x >> 3;
  int wid = (blockIdx.x & 7) * per + (blockIdx.x >> 3);
  int tpe = ntn * ntm;
  int e = wid / tpe;
  int rem = wid - e * tpe;
  int mt = rem / ntn;        // m-tile (outer within expert)
  int nt = rem - mt * ntn;   // n-tile (inner -> A-tile reuse in time)
  int m0 = mt * BM;
  int n0 = nt * BN;

  const u16* A = A_base + (long)e * a_estride;
  const u16* Wt = Wt_base + (long)e * w_estride;
  const float* bias = bias_base + (long)e * b_estride;
  u16* C = C_base + (long)e * c_estride;

  // [row][64 k-elems] = 128B rows; A 16KB, B 8KB; dual buffers = 48KB
  __shared__ u16 As0[BM * 64];
  __shared__ u16 As1[BM * 64];
  __shared__ u16 Bs0[BN * 64];
  __shared__ u16 Bs1[BN * 64];

  int tid = threadIdx.x;
  int lane = tid & 63;
  int w = tid >> 6;            // wave 0..3 in 2x2
  int wm = (w >> 1) * 64;      // 0 / 64
  int wn = (w & 1) * 32;       // 0 / 32
  int col = lane & 15;
  int quad = lane >> 4;

  floatx4 acc[4][2] = {};

  // staging: thread -> (row = tid>>3 within 32-row group, slot = tid&7),
  // global chunk pre-swizzled: (tid&7) ^ ((tid>>3)&7)
  int srow = tid >> 3;                             // 0..31
  int gchunk = (tid & 7) ^ (srow & 7);
  const u16* gA = &A[(long)(m0 + srow) * K + gchunk * 8];
  const u16* gB = &Wt[(long)(n0 + srow) * K + gchunk * 8];
  long rowK = (long)32 * K;                        // 32 rows per instruction

  // read: slot s(kk) = (kk*4 + quad) ^ (col&7); row&7==col&7 cancels the
  // staging XOR -> identical data, conflict-free banking (R5 verified).
  int s0 = (quad ^ (col & 7)) * 8;                 // u16 offset of 16B slot
  int aRow = (wm + col) * 64;
  int bRow = (wn + col) * 64;

#define STAGE(Asb, Bsb, k0)                                        \
  do {                                                             \
    gld_lds16(gA + (k0),            &Asb[(size_t)tid * 8]);        \
    gld_lds16(gA + rowK + (k0),     &Asb[2048 + (size_t)tid * 8]); \
    gld_lds16(gA + 2 * rowK + (k0), &Asb[4096 + (size_t)tid * 8]); \
    gld_lds16(gA + 3 * rowK + (k0), &Asb[6144 + (size_t)tid * 8]); \
    gld_lds16(gB + (k0),            &Bsb[(size_t)tid * 8]);        \
    gld_lds16(gB + rowK + (k0),     &Bsb[2048 + (size_t)tid * 8]); \
  } while (0)

#define COMPUTE(Asb, Bsb)                                               \
  do {                                                                  \
    _Pragma("unroll")                                                   \
    for (int kk = 0; kk < 2; ++kk) {                                    \
      int s = s0 ^ (kk * 32);                                           \
      bf16x8 xf[4], wf[2];                                              \
      _Pragma("unroll")                                                 \
      for (int t4 = 0; t4 < 4; ++t4)                                    \
        xf[t4] = __builtin_bit_cast(bf16x8,                             \
            *reinterpret_cast<const u16x8*>(&Asb[aRow + t4 * 1024 + s])); \
      _Pragma("unroll")                                                 \
      for (int j = 0; j < 2; ++j)                                       \
        wf[j] = __builtin_bit_cast(bf16x8,                              \
            *reinterpret_cast<const u16x8*>(&Bsb[bRow + j * 1024 + s])); \
      _Pragma("unroll")                                                 \
      for (int i = 0; i < 4; ++i)                                       \
        _Pragma("unroll")                                               \
        for (int j = 0; j < 2; ++j)                                     \
          acc[i][j] = __builtin_amdgcn_mfma_f32_16x16x32_bf16(          \
              wf[j], xf[i], acc[i][j], 0, 0, 0);                        \
    }                                                                   \
  } while (0)

  // prologue: tile 0 into buf0
  STAGE(As0, Bs0, 0);
  __syncthreads();  // drain prologue DMA

  for (int k0 = 0; k0 < K; k0 += 128) {
    // even tile: prefetch buf1, compute buf0
    if (k0 + 64 < K) STAGE(As1, Bs1, k0 + 64);
    COMPUTE(As0, Bs0);
    __syncthreads();  // drains vmcnt (buf1 DMA) + lgkm; WAR for buf0
    // odd tile: prefetch buf0, compute buf1
    if (k0 + 128 < K) STAGE(As0, Bs0, k0 + 128);
    COMPUTE(As1, Bs1);
    __syncthreads();  // drains vmcnt (buf0 DMA) + lgkm; WAR for buf1
  }
#undef STAGE
#undef COMPUTE

  // epilogue: lane holds m = m0+wm+i*16+col, n = n0+wn+j*16+quad*4+[0..3]
  float4 b4[2];
#pragma unroll
  for (int j = 0; j < 2; ++j)
    b4[j] = *reinterpret_cast<const float4*>(
        &bias[n0 + wn + j * 16 + quad * 4]);
#pragma unroll
  for (int i = 0; i < 4; ++i) {
    int m = m0 + wm + i * 16 + col;
#pragma unroll
    for (int j = 0; j < 2; ++j) {
      int nn = n0 + wn + j * 16 + quad * 4;
      u16x4 o;
      o.x = f2bf(elu1(acc[i][j][0] + b4[j].x));
      o.y = f2bf(elu1(acc[i][j][1] + b4[j].y));
      o.z = f2bf(elu1(acc[i][j][2] + b4[j].z));
      o.w = f2bf(elu1(acc[i][j][3] + b4[j].w));
      *reinterpret_cast<u16x4*>(&C[(long)m * N + nn]) = o;
    }
  }
}

// ---------------- fused L4: gate + softmax + expert heads + combine -------
__global__ __launch_bounds__(256) void final_combine_kernel(
    const u16* __restrict__ h3, const u16* __restrict__ W4t,
    const u16* __restrict__ gW4t, const float* __restrict__ eb4,
    const float* __restrict__ gb4, float* __restrict__ out) {
  const int H3 = 256;
  int tid = threadIdx.x;
  int lane = tid & 63;
  int w = tid >> 6;  // wave 0..3
  int col = lane & 15;
  int quad = lane >> 4;
  int r0 = blockIdx.x * 16;

  // ---- gate logits (every wave, same 16 rows) ----
  floatx4 g0 = {}, g1 = {};
  const u16* h3g = h3 + (long)E_EXP * B_SZ * H3;
#pragma unroll
  for (int k0 = 0; k0 < 256; k0 += 32) {
    bf16x8 a = ld_bf8(&h3g[(long)(r0 + col) * H3 + k0 + quad * 8]);
    bf16x8 b0 = ld_bf8(&gW4t[(long)col * H3 + k0 + quad * 8]);
    bf16x8 b1 = ld_bf8(&gW4t[(long)(16 + col) * H3 + k0 + quad * 8]);
    g0 = __builtin_amdgcn_mfma_f32_16x16x32_bf16(a, b0, g0, 0, 0, 0);
    g1 = __builtin_amdgcn_mfma_f32_16x16x32_bf16(a, b1, g1, 0, 0, 0);
  }

  // ---- softmax over 20 logits per row ----
  float w0[4], w1[4];
  float gbc0 = gb4[col];
  float gbc1 = (col < 4) ? gb4[16 + col] : 0.f;
#pragma unroll
  for (int r = 0; r < 4; ++r) {
    float v0 = g0[r] + gbc0;
    float v1 = (col < 4) ? (g1[r] + gbc1) : -1e30f;
    float m = fmaxf(v0, v1);
#pragma unroll
    for (int s = 1; s < 16; s <<= 1) m = fmaxf(m, __shfl_xor(m, s, 64));
    float e0 = __expf(v0 - m);
    float e1 = (col < 4) ? __expf(v1 - m) : 0.f;
    float ssum = e0 + e1;
#pragma unroll
    for (int s = 1; s < 16; s <<= 1) ssum += __shfl_xor(ssum, s, 64);
    w0[r] = e0 / ssum;
    w1[r] = e1 / ssum;
  }

  // ---- this wave's experts: w, w+4, w+8, w+12, w+16 ----
  floatx4 o0 = {}, o1 = {};
  for (int e = w; e < E_EXP; e += 4) {
    floatx4 a0 = {}, a1 = {};
    const u16* he = h3 + (long)e * B_SZ * H3;
    const u16* we = W4t + (long)e * 32 * H3;
#pragma unroll
    for (int k0 = 0; k0 < 256; k0 += 32) {
      bf16x8 a = ld_bf8(&he[(long)(r0 + col) * H3 + k0 + quad * 8]);
      bf16x8 b0 = ld_bf8(&we[(long)col * H3 + k0 + quad * 8]);
      bf16x8 b1 = ld_bf8(&we[(long)(16 + col) * H3 + k0 + quad * 8]);
      a0 = __builtin_amdgcn_mfma_f32_16x16x32_bf16(a, b0, a0, 0, 0, 0);
      a1 = __builtin_amdgcn_mfma_f32_16x16x32_bf16(a, b1, a1, 0, 0, 0);
    }
    float be0 = eb4[e * 32 + col];
    float be1 = eb4[e * 32 + 16 + col];
    int src = (lane & 48) + (e & 15);
#pragma unroll
    for (int r = 0; r < 4; ++r) {
      float wr = __shfl((e < 16) ? w0[r] : w1[r], src, 64);
      o0[r] += wr * (a0[r] + be0);
      o1[r] += wr * (a1[r] + be1);
    }
  }

  // ---- cross-wave reduce in LDS ----
  __shared__ float red[3][64][8];
  if (w > 0) {
#pragma unroll
    for (int r = 0; r < 4; ++r) {
      red[w - 1][lane][r] = o0[r];
      red[w - 1][lane][4 + r] = o1[r];
    }
  }
  __syncthreads();
  if (w == 0) {
#pragma unroll
    for (int ww = 0; ww < 3; ++ww)
#pragma unroll
      for (int r = 0; r < 4; ++r) {
        o0[r] += red[ww][lane][r];
        o1[r] += red[ww][lane][4 + r];
      }
#pragma unroll
    for (int r = 0; r < 4; ++r) {
      int row = r0 + quad * 4 + r;
      out[(long)row * 32 + col] = o0[r];
      out[(long)row * 32 + 16 + col] = o1[r];
    }
  }
}

// ---------------- host launch ----------------

static inline size_t align256(size_t x) { return (x + 255) & ~(size_t)255; }

extern "C" void kernel_launch(void* const* d_in, const int* in_sizes, int n_in,
                              void* d_out, int out_size, void* d_ws,
                              size_t ws_size, hipStream_t stream) {
  const float* obs = (const float*)d_in[0];
  const float* eW1 = (const float*)d_in[1];
  const float* eb1 = (const float*)d_in[2];
  const float* eW2 = (const float*)d_in[3];
  const float* eb2 = (const float*)d_in[4];
  const float* eW3 = (const float*)d_in[5];
  const float* eb3 = (const float*)d_in[6];
  const float* eW4 = (const float*)d_in[7];
  const float* eb4 = (const float*)d_in[8];
  const float* gW1 = (const float*)d_in[9];
  const float* gb1 = (const float*)d_in[10];
  const float* gW2 = (const float*)d_in[11];
  const float* gb2 = (const float*)d_in[12];
  const float* gW3 = (const float*)d_in[13];
  const float* gb3 = (const float*)d_in[14];
  const float* gW4 = (const float*)d_in[15];
  const float* gb4 = (const float*)d_in[16];
  float* out = (float*)d_out;
  char* ws = (char*)d_ws;

  // fixed workspace region
  size_t off = 0;
  size_t OFF_OBS = off;  off = align256(off + (size_t)B_SZ * 512 * 2);
  size_t OFF_W1T = off;  off = align256(off + (size_t)NE * 1024 * 512 * 2);
  size_t OFF_W2T = off;  off = align256(off + (size_t)NE * 512 * 1024 * 2);
  size_t OFF_W3T = off;  off = align256(off + (size_t)NE * 256 * 512 * 2);
  size_t OFF_W4T = off;  off = align256(off + (size_t)E_EXP * 32 * 256 * 2);
  size_t OFF_GW4T = off; off = align256(off + (size_t)32 * 256 * 2);
  size_t OFF_B1 = off;   off = align256(off + (size_t)NE * 1024 * 4);
  size_t OFF_B2 = off;   off = align256(off + (size_t)NE * 512 * 4);
  size_t OFF_B3 = off;   off = align256(off + (size_t)NE * 256 * 4);
  size_t OFF_H3 = off;   off = align256(off + (size_t)NE * B_SZ * 256 * 2);

  // adaptive batch-chunked h1/h2: every dispatch covers all 21 experts
  int chunk = B_SZ;
  size_t OFF_H1 = off;
  while (chunk > 512) {
    size_t need = (size_t)NE * chunk * 1024 * 2 + (size_t)NE * chunk * 512 * 2;
    if (OFF_H1 + need <= ws_size) break;
    chunk >>= 1;
  }
  size_t OFF_H2 = align256(OFF_H1 + (size_t)NE * chunk * 1024 * 2);

  u16* obs_bf = (u16*)(ws + OFF_OBS);
  u16* W1t = (u16*)(ws + OFF_W1T);
  u16* W2t = (u16*)(ws + OFF_W2T);
  u16* W3t = (u16*)(ws + OFF_W3T);
  u16* W4t = (u16*)(ws + OFF_W4T);
  u16* gW4t = (u16*)(ws + OFF_GW4T);
  float* b1 = (float*)(ws + OFF_B1);
  float* b2 = (float*)(ws + OFF_B2);
  float* b3 = (float*)(ws + OFF_B3);
  u16* h3 = (u16*)(ws + OFF_H3);
  u16* h1 = (u16*)(ws + OFF_H1);
  u16* h2 = (u16*)(ws + OFF_H2);

  // --- prep: obs convert + bias concat (1), all transposes (1) ---
  prep_small_kernel<<<2048 + (NE * 1792 + 255) / 256, 256, 0, stream>>>(
      obs, obs_bf, eb1, gb1, eb2, gb2, eb3, gb3, b1, b2, b3);
  transpose_all_kernel<<<TRANS_BLOCKS, 256, 0, stream>>>(
      eW1, gW1, eW2, gW2, eW3, gW3, eW4, gW4, W1t, W2t, W3t, W4t, gW4t);

  int ntm = chunk / BM;
  // --- trunk layers 1..3, batch-chunked, XCD-clustered 1-D grids ---
  for (int bc = 0; bc < B_SZ; bc += chunk) {
    gemm_bias_elu_kernel<<<NE * 16 * ntm, 256, 0, stream>>>(
        obs_bf + (size_t)bc * 512, 0L,
        W1t, (long)1024 * 512,
        b1, 1024L,
        h1, (long)chunk * 1024, chunk, 1024, 512, 16, ntm);
    gemm_bias_elu_kernel<<<NE * 8 * ntm, 256, 0, stream>>>(
        h1, (long)chunk * 1024,
        W2t, (long)512 * 1024,
        b2, 512L,
        h2, (long)chunk * 512, chunk, 512, 1024, 8, ntm);
    gemm_bias_elu_kernel<<<NE * 4 * ntm, 256, 0, stream>>>(
        h2, (long)chunk * 512,
        W3t, (long)256 * 512,
        b3, 256L,
        h3 + (size_t)bc * 256, (long)B_SZ * 256, chunk, 256, 512, 4, ntm);
  }

  // --- fused layer-4 + softmax + combine ---
  final_combine_kernel<<<B_SZ / 16, 256, 0, stream>>>(h3, W4t, gW4t, eb4, gb4,
                                                      out);
}